// Round 20
// baseline (230.288 us; speedup 1.0000x reference)
//
#include <hip/hip_runtime.h>
#include <hip/hip_bf16.h>
#include <math.h>
#include <stdint.h>

typedef __bf16 bf16;
typedef __bf16 bf16x2 __attribute__((ext_vector_type(2)));
typedef __bf16 bf16x4 __attribute__((ext_vector_type(4)));
typedef __bf16 bf16x8 __attribute__((ext_vector_type(8)));
typedef float f32x4 __attribute__((ext_vector_type(4)));
typedef float f32x16 __attribute__((ext_vector_type(16)));
typedef unsigned uint2v __attribute__((ext_vector_type(2)));
typedef unsigned uint4v __attribute__((ext_vector_type(4)));

#define MFMA16(a, b, c) __builtin_amdgcn_mfma_f32_16x16x32_bf16((a), (b), (c), 0, 0, 0)
#define MFMA32(a, b, c) __builtin_amdgcn_mfma_f32_32x32x16_bf16((a), (b), (c), 0, 0, 0)

constexpr int EMB = 1024;
constexpr int SEQ = 2048;
constexpr int BATCH = 2;
constexpr int NTOK = BATCH * SEQ;   // 4096
constexpr int FFN = 4 * EMB;        // 4096
constexpr int HEADS = 16;
constexpr int HDIM = 64;

// q pre-scale: 1/sqrt(64) * log2(e)  (softmax runs in exp2 domain)
#define QSCALE 0.18033688011112042f

// async 16B global -> LDS (wave-uniform base + lane*16 destination)
__device__ __forceinline__ void gload16(const void* g, void* l) {
    __builtin_amdgcn_global_load_lds(
        (const __attribute__((address_space(1))) void*)g,
        (__attribute__((address_space(3))) void*)l,
        16, 0, 0);
}

// cross-half (lane i <-> lane i+32) max/sum via v_permlane32_swap (VALU pipe)
__device__ __forceinline__ float xhalf_max(float x) {
    unsigned u = __float_as_uint(x);
    uint2v r = __builtin_amdgcn_permlane32_swap(u, u, false, false);
    return fmaxf(__uint_as_float(r[0]), __uint_as_float(r[1]));
}
__device__ __forceinline__ float xhalf_sum(float x) {
    unsigned u = __float_as_uint(x);
    uint2v r = __builtin_amdgcn_permlane32_swap(u, u, false, false);
    return __uint_as_float(r[0]) + __uint_as_float(r[1]);
}

__device__ __forceinline__ unsigned pkbf(float a, float b) {
    bf16x2 v;
    v[0] = (bf16)a;
    v[1] = (bf16)b;
    return __builtin_bit_cast(unsigned, v);
}

// gelu_tanh(u) = u * sigmoid(2w), w = c*(u + 0.044715 u^3); exp2 domain
__device__ __forceinline__ float gelu_f(float u) {
    float w_ = 0.7978845608028654f * (u + 0.044715f * u * u * u);
    float z = __builtin_amdgcn_exp2f(-2.8853900817779268f * w_);
    return u / (1.f + z);
}

// ---------------- LayerNorm: fp32 in -> bf16 out --------------------------
__global__ __launch_bounds__(256) void ln_kernel(const float* __restrict__ x,
                                                 const float* __restrict__ g,
                                                 const float* __restrict__ b,
                                                 bf16* __restrict__ out) {
    int row = blockIdx.x;
    int t = threadIdx.x;
    float4 v = reinterpret_cast<const float4*>(x + (size_t)row * EMB)[t];
    float s = v.x + v.y + v.z + v.w;
    float s2 = v.x * v.x + v.y * v.y + v.z * v.z + v.w * v.w;
#pragma unroll
    for (int o = 1; o < 64; o <<= 1) {
        s += __shfl_xor(s, o);
        s2 += __shfl_xor(s2, o);
    }
    __shared__ float ps[4], ps2[4];
    int w = t >> 6;
    if ((t & 63) == 0) { ps[w] = s; ps2[w] = s2; }
    __syncthreads();
    s = ps[0] + ps[1] + ps[2] + ps[3];
    s2 = ps2[0] + ps2[1] + ps2[2] + ps2[3];
    float mean = s * (1.f / EMB);
    float var = s2 * (1.f / EMB) - mean * mean;
    float rstd = rsqrtf(var + 1e-5f);
    float4 gv = reinterpret_cast<const float4*>(g)[t];
    float4 bv = reinterpret_cast<const float4*>(b)[t];
    bf16* op = out + (size_t)row * EMB + t * 4;
    op[0] = (bf16)(gv.x * (v.x - mean) * rstd + bv.x);
    op[1] = (bf16)(gv.y * (v.y - mean) * rstd + bv.y);
    op[2] = (bf16)(gv.z * (v.z - mean) * rstd + bv.z);
    op[3] = (bf16)(gv.w * (v.w - mean) * rstd + bv.w);
}

// ---- fused transpose + cast: all 6 weights, W[K][N] f32 -> Wt[N][K] bf16 --
__global__ __launch_bounds__(256) void transpose_all(
    const float* __restrict__ Wq, const float* __restrict__ Wk,
    const float* __restrict__ Wv, const float* __restrict__ Wo,
    const float* __restrict__ W1, const float* __restrict__ W2,
    bf16* __restrict__ Wqkvt, bf16* __restrict__ Wot,
    bf16* __restrict__ W1t, bf16* __restrict__ W2t) {
    int b = blockIdx.x;
    const float* W;
    bf16* Wt;
    int K, N, tile;
    if (b < 4096) {
        int w = b >> 10;
        tile = b & 1023;
        W = (w == 0) ? Wq : (w == 1) ? Wk : (w == 2) ? Wv : Wo;
        Wt = (w == 3) ? Wot : Wqkvt + (size_t)w * EMB * EMB;
        K = EMB; N = EMB;
    } else if (b < 8192) {
        tile = b - 4096; W = W1; Wt = W1t; K = EMB; N = FFN;
    } else {
        tile = b - 8192; W = W2; Wt = W2t; K = FFN; N = EMB;
    }
    int ntx = N / 32;
    int n0 = (tile % ntx) * 32, k0 = (tile / ntx) * 32;
    __shared__ float tl[32][33];
    int tx = threadIdx.x & 31, ty = threadIdx.x >> 5;  // 32 x 8
#pragma unroll
    for (int i = 0; i < 4; i++)
        tl[ty + 8 * i][tx] = W[(size_t)(k0 + ty + 8 * i) * N + n0 + tx];
    __syncthreads();
#pragma unroll
    for (int i = 0; i < 4; i++)
        Wt[(size_t)(n0 + ty + 8 * i) * K + k0 + tx] = (bf16)tl[tx][ty + 8 * i];
}

// ---------------- V transpose: [B,H,S,64] -> [B,H,64,S] bf16 --------------
__global__ __launch_bounds__(256) void vtrans(const bf16* __restrict__ v,
                                              bf16* __restrict__ vt) {
    int bh = blockIdx.y;
    int s0 = blockIdx.x * 64;
    const bf16* src = v + (size_t)bh * SEQ * HDIM + (size_t)s0 * HDIM;
    bf16* dst = vt + (size_t)bh * HDIM * SEQ + s0;
    __shared__ bf16 tile[64][72];
    int t = threadIdx.x;
    int s = t >> 2, d0 = (t & 3) * 16;
    bf16x8 a = *reinterpret_cast<const bf16x8*>(src + s * HDIM + d0);
    bf16x8 b = *reinterpret_cast<const bf16x8*>(src + s * HDIM + d0 + 8);
#pragma unroll
    for (int e = 0; e < 8; e++) {
        tile[d0 + e][s] = a[e];
        tile[d0 + 8 + e][s] = b[e];
    }
    __syncthreads();
    int d = t >> 2, c0 = (t & 3) * 16;
    bf16x8 o0 = *reinterpret_cast<const bf16x8*>(&tile[d][c0]);
    bf16x8 o1 = *reinterpret_cast<const bf16x8*>(&tile[d][c0 + 8]);
    *reinterpret_cast<bf16x8*>(dst + (size_t)d * SEQ + c0) = o0;
    *reinterpret_cast<bf16x8*>(dst + (size_t)d * SEQ + c0 + 8) = o1;
}

// ---------------- 8-phase 256x256 GEMM, counted-vmcnt (T1+T2+T3+T4+T5) ----
// XCD-bijective block swizzle (per z-plane; nwg % 8 == 0 for all call sites):
// each XCD gets a contiguous column-major tile run -> B panels L2-shared.
// MODE 0: fused QKV scatter -> bf16 q/k/v [B,H,S,64] (q scaled QSCALE)
// MODE 2: out bf16 = gelu(acc + bias)
// MODE 3: bf16 partial tile -> z<2: outB + z*NTOK*EMB ; z==2: outB2
template <int MODE>
__global__ __launch_bounds__(512, 1) void gemm8p(const bf16* __restrict__ A,
                                                 const bf16* __restrict__ Bt,
                                                 int K, int N,
                                                 bf16* __restrict__ outB,
                                                 bf16* __restrict__ outB2,
                                                 const float* __restrict__ bias) {
    extern __shared__ char smem[];  // [buf][A 32K | B 32K] x2 = 128 KiB
    int t = threadIdx.x;
    int wave = t >> 6, lane = t & 63;
    int wr = wave >> 2, wc = wave & 3;      // 2 x 4 wave grid
    int lr = lane & 15, lg = lane >> 4;

    // T1: bijective XCD swizzle of the (x,y) tile id
    int gx = gridDim.x, nwg = gx * gridDim.y;
    int wg = blockIdx.x + blockIdx.y * gx;
    int sw = (wg & 7) * (nwg >> 3) + (wg >> 3);
    int row0 = (sw % gx) * 256;
    int col0 = (sw / gx) * 256;

    int tilesAll = K / 64;
    int nz = gridDim.z, z = blockIdx.z;
    int base = tilesAll / nz, rem = tilesAll - base * nz;
    int myT = base + (z < rem ? 1 : 0);
    int tBeg = z * base + (z < rem ? z : rem);

    const char* aSrc[4];
    const char* bSrc[4];
#pragma unroll
    for (int i = 0; i < 4; i++) {
        int f = t + i * 512;
        int gr = f >> 3, gk = f & 7;
        aSrc[i] = (const char*)A + ((size_t)(row0 + gr) * K + ((gk ^ (gr & 7)) << 3)) * 2
                  + (size_t)tBeg * 128;
        bSrc[i] = (const char*)Bt + ((size_t)(col0 + gr) * K + ((gk ^ (gr & 7)) << 3)) * 2
                  + (size_t)tBeg * 128;
    }

    f32x4 acc[8][4];
#pragma unroll
    for (int m = 0; m < 8; m++)
#pragma unroll
        for (int n = 0; n < 4; n++) acc[m][n] = f32x4{0.f, 0.f, 0.f, 0.f};

    // prologue: stage tile 0 into buf 0; issue order B0,B1,B2,B3,A0,A2,A1,A3
    gload16(bSrc[0], smem + 32768 + (t + 0 * 512) * 16);
    gload16(bSrc[1], smem + 32768 + (t + 1 * 512) * 16);
    gload16(bSrc[2], smem + 32768 + (t + 2 * 512) * 16);
    gload16(bSrc[3], smem + 32768 + (t + 3 * 512) * 16);
    gload16(aSrc[0], smem + (t + 0 * 512) * 16);
    gload16(aSrc[2], smem + (t + 2 * 512) * 16);
    gload16(aSrc[1], smem + (t + 1 * 512) * 16);
    gload16(aSrc[3], smem + (t + 3 * 512) * 16);
    asm volatile("s_waitcnt vmcnt(2)" ::: "memory");
    __builtin_amdgcn_s_barrier();

    for (int tk = 0; tk < myT; tk++) {
        int cur = tk & 1;
        const char* la = smem + cur * 65536;
        const char* lb = la + 32768;
        char* na = smem + (cur ^ 1) * 65536;
        bool stage = (tk + 1 < myT);

        bf16x8 bfr[2][4];
#pragma unroll
        for (int ph = 0; ph < 4; ph++) {
            constexpr int PH_KH[4] = {0, 0, 1, 1};
            constexpr int PH_MH[4] = {0, 1, 0, 1};
            const int kh = PH_KH[ph], mh = PH_MH[ph];
            bf16x8 afr[4];
#pragma unroll
            for (int m = 0; m < 4; m++) {
                int row = wr * 128 + (mh * 4 + m) * 16 + lr;
                int gk = kh * 4 + lg;
                afr[m] = *reinterpret_cast<const bf16x8*>(
                    la + row * 128 + ((gk ^ (row & 7)) << 4));
            }
            if (mh == 0) {
#pragma unroll
                for (int n = 0; n < 4; n++) {
                    int row = wc * 64 + n * 16 + lr;
                    int gk = kh * 4 + lg;
                    bfr[kh][n] = *reinterpret_cast<const bf16x8*>(
                        lb + row * 128 + ((gk ^ (row & 7)) << 4));
                }
            }
            if (stage) {
                if (ph == 0) {
                    gload16(bSrc[0] + 128, na + 32768 + (t + 0 * 512) * 16);
                    gload16(bSrc[1] + 128, na + 32768 + (t + 1 * 512) * 16);
                } else if (ph == 1) {
                    gload16(bSrc[2] + 128, na + 32768 + (t + 2 * 512) * 16);
                    gload16(bSrc[3] + 128, na + 32768 + (t + 3 * 512) * 16);
                } else if (ph == 2) {
                    gload16(aSrc[0] + 128, na + (t + 0 * 512) * 16);
                    gload16(aSrc[2] + 128, na + (t + 2 * 512) * 16);
                } else {
                    gload16(aSrc[1] + 128, na + (t + 1 * 512) * 16);
                    gload16(aSrc[3] + 128, na + (t + 3 * 512) * 16);
                }
            }
            __builtin_amdgcn_s_barrier();
            __builtin_amdgcn_s_setprio(1);
#pragma unroll
            for (int m = 0; m < 4; m++)
#pragma unroll
                for (int n = 0; n < 4; n++)
                    acc[mh * 4 + m][n] = MFMA16(afr[m], bfr[kh][n], acc[mh * 4 + m][n]);
            __builtin_amdgcn_s_setprio(0);
            if (ph == 0 || ph == 3)
                asm volatile("s_waitcnt vmcnt(2)" ::: "memory");
            __builtin_amdgcn_s_barrier();
        }
#pragma unroll
        for (int i = 0; i < 4; i++) { aSrc[i] += 128; bSrc[i] += 128; }
    }

    float bi[4];
    if (MODE == 2) {
#pragma unroll
        for (int n = 0; n < 4; n++) bi[n] = bias[col0 + wc * 64 + n * 16 + lr];
    }
    bf16* pd = outB;
    if (MODE == 3) pd = (z < 2) ? outB + (size_t)z * ((size_t)NTOK * EMB) : outB2;
#pragma unroll
    for (int mf = 0; mf < 8; mf++) {
#pragma unroll
        for (int r = 0; r < 4; r++) {
            int row = row0 + wr * 128 + mf * 16 + 4 * lg + r;
#pragma unroll
            for (int n = 0; n < 4; n++) {
                int col = col0 + wc * 64 + n * 16 + lr;
                float v = acc[mf][n][r];
                if (MODE == 0) {
                    int b_ = row >> 11, s_ = row & 2047;
                    int which = col >> 10, rem_ = col & 1023;
                    int h_ = rem_ >> 6, d_ = rem_ & 63;
                    float sc = (which == 0) ? QSCALE : 1.0f;
                    outB[(size_t)which * (NTOK * EMB) +
                         (((size_t)(b_ * HEADS + h_) * SEQ + s_) << 6) + d_] =
                        (bf16)(v * sc);
                } else if (MODE == 2) {
                    outB[(size_t)row * N + col] = (bf16)gelu_f(v + bi[n]);
                } else {
                    pd[(size_t)row * N + col] = (bf16)v;
                }
            }
        }
    }
}

// ------- FFN2 reduce: out = x1 + p0 + p1 + p2 + bias (all fp32 out) -------
__global__ __launch_bounds__(256) void ffn2_reduce(const float* __restrict__ x1,
                                                   const bf16* __restrict__ p01,
                                                   const bf16* __restrict__ p2,
                                                   const float* __restrict__ bias,
                                                   float* __restrict__ out) {
    constexpr int UNITS = NTOK * EMB / 4;
    const bf16* p1 = p01 + (size_t)NTOK * EMB;
    for (int i = blockIdx.x * 256 + threadIdx.x; i < UNITS; i += gridDim.x * 256) {
        float4 r = reinterpret_cast<const float4*>(x1)[i];
        float4 bv = reinterpret_cast<const float4*>(bias)[i & (EMB / 4 - 1)];
        bf16x4 a0 = reinterpret_cast<const bf16x4*>(p01)[i];
        bf16x4 a1 = reinterpret_cast<const bf16x4*>(p1)[i];
        bf16x4 a2 = reinterpret_cast<const bf16x4*>(p2)[i];
        r.x += (float)a0[0] + (float)a1[0] + (float)a2[0] + bv.x;
        r.y += (float)a0[1] + (float)a1[1] + (float)a2[1] + bv.y;
        r.z += (float)a0[2] + (float)a1[2] + (float)a2[2] + bv.z;
        r.w += (float)a0[3] + (float)a1[3] + (float)a2[3] + bv.w;
        reinterpret_cast<float4*>(out)[i] = r;
    }
}

// ---------------- LDS-staged GEMM (m97 structure, + T1 swizzle) -----------
// MODE 1: out f32 = resid + acc + bias
template <int BM, int BN, int BK, int MODE>
__global__ __launch_bounds__(256) void gemm_lds(const bf16* __restrict__ A,
                                                const bf16* __restrict__ Bt,
                                                int M, int N, int K,
                                                float* __restrict__ outF,
                                                bf16* __restrict__ outB,
                                                const float* __restrict__ bias,
                                                const float* __restrict__ resid) {
    constexpr int MR = BM / 32;
    constexpr int NR = BN / 32;
    constexpr int ACH = (BM * BK * 2) / 4096;
    constexpr int BCH = (BN * BK * 2) / 4096;
    __shared__ bf16 sA[BM * BK];
    __shared__ bf16 sB[BN * BK];
    int t = threadIdx.x;
    int wave = t >> 6, lane = t & 63;
    int wr = wave >> 1, wc = wave & 1;
    int lr = lane & 15, lg = lane >> 4;

    // T1: bijective XCD swizzle (nwg % 8 == 0 at call site: 32x16=512)
    int gx = gridDim.x, nwg = gx * gridDim.y;
    int wg = blockIdx.x + blockIdx.y * gx;
    int sw = (wg & 7) * (nwg >> 3) + (wg >> 3);
    int row0 = (sw % gx) * BM;
    int col0 = (sw / gx) * BN;

    const char* aS[ACH];
    const char* bS[BCH];
#pragma unroll
    for (int c = 0; c < ACH; c++) {
        int o = (t + c * 256) * 16;
        aS[c] = (const char*)A + (size_t)(row0 + o / (2 * BK)) * K * 2 + (o & (2 * BK - 1));
    }
#pragma unroll
    for (int c = 0; c < BCH; c++) {
        int o = (t + c * 256) * 16;
        bS[c] = (const char*)Bt + (size_t)(col0 + o / (2 * BK)) * K * 2 + (o & (2 * BK - 1));
    }

    f32x4 acc[MR][NR];
#pragma unroll
    for (int m = 0; m < MR; m++)
#pragma unroll
        for (int n = 0; n < NR; n++) acc[m][n] = f32x4{0.f, 0.f, 0.f, 0.f};

    for (int k0 = 0; k0 < K; k0 += BK) {
        __syncthreads();
#pragma unroll
        for (int c = 0; c < ACH; c++)
            gload16(aS[c], (char*)sA + (t + c * 256) * 16);
#pragma unroll
        for (int c = 0; c < BCH; c++)
            gload16(bS[c], (char*)sB + (t + c * 256) * 16);
#pragma unroll
        for (int c = 0; c < ACH; c++) aS[c] += 2 * BK;
#pragma unroll
        for (int c = 0; c < BCH; c++) bS[c] += 2 * BK;
        __syncthreads();

#pragma unroll
        for (int ks = 0; ks < BK / 32; ks++) {
            bf16x8 a[MR], b[NR];
#pragma unroll
            for (int m = 0; m < MR; m++)
                a[m] = *reinterpret_cast<const bf16x8*>(
                    sA + (wr * (BM / 2) + m * 16 + lr) * BK + ks * 32 + 8 * lg);
#pragma unroll
            for (int n = 0; n < NR; n++)
                b[n] = *reinterpret_cast<const bf16x8*>(
                    sB + (wc * (BN / 2) + n * 16 + lr) * BK + ks * 32 + 8 * lg);
#pragma unroll
            for (int m = 0; m < MR; m++)
#pragma unroll
                for (int n = 0; n < NR; n++)
                    acc[m][n] = MFMA16(a[m], b[n], acc[m][n]);
        }
    }

#pragma unroll
    for (int m = 0; m < MR; m++) {
#pragma unroll
        for (int r = 0; r < 4; r++) {
            int row = row0 + wr * (BM / 2) + m * 16 + 4 * lg + r;
#pragma unroll
            for (int n = 0; n < NR; n++) {
                int col = col0 + wc * (BN / 2) + n * 16 + lr;
                float v = acc[m][n][r];
                size_t idx = (size_t)row * N + col;
                outF[idx] = resid[idx] + v + bias[col];
            }
        }
    }
}

// ---------------- causal flash attention (v12b, unchanged) -----------------
__global__ __launch_bounds__(256, 2) void attn_kernel(const bf16* __restrict__ q,
                                                      const bf16* __restrict__ k,
                                                      const bf16* __restrict__ vt,
                                                      bf16* __restrict__ ctx) {
    int wg = blockIdx.x;
    int wgid = (wg & 7) * 64 + (wg >> 3);   // bijective: 512 = 8 XCD * 64
    int bh = wgid >> 4;                     // 16 blocks/head, 4 heads/XCD
    int pair = wgid & 15;
    const bf16* qh = q + (size_t)bh * SEQ * HDIM;
    const bf16* kh = k + (size_t)bh * SEQ * HDIM;
    const bf16* vh = vt + (size_t)bh * HDIM * SEQ;  // [64][2048]
    int t = threadIdx.x;
    int wave = t >> 6, lane = t & 63;
    int ql = lane & 31, hi = lane >> 5;

    int s64 = (wave < 2) ? (31 - pair) : pair;   // q-span in 64-row units
    int qrow = s64 * 64 + (wave & 1) * 32;
    int myNc = (s64 >> 1) + 1;                   // 128-key chunks this wave needs
    int ncAll = ((31 - pair) >> 1) + 1;          // chunks staged (heavy range)

    __shared__ bf16 sK[2][128 * 64];     // [key][d], granule-swizzled (16 KB/buf)
    __shared__ bf16 sV[2][2][64 * 64];   // [half][d][key], granule-swizzled

    int grow = t >> 3, gg = t & 7;
    const bf16* kS[4];
#pragma unroll
    for (int i = 0; i < 4; i++)
        kS[i] = kh + (size_t)(grow + 32 * i) * HDIM + ((gg ^ ((grow + 32 * i) & 7)) << 3);
    const bf16* vS[2];
#pragma unroll
    for (int i = 0; i < 2; i++)
        vS[i] = vh + (size_t)(grow + 32 * i) * SEQ + ((gg ^ ((grow + 32 * i) & 7)) << 3);
    char* kD = (char*)&sK[0][0] + wave * 1024;
    char* vD = (char*)&sV[0][0][0] + wave * 1024;

    int b_ = bh >> 4, h_ = bh & 15;

    // Q fragments (B-operand): col=q=ql, k = 8*hi+e over d-slices ks*16
    bf16x8 qf[4];
#pragma unroll
    for (int ks = 0; ks < 4; ks++)
        qf[ks] = *reinterpret_cast<const bf16x8*>(
            qh + (size_t)(qrow + ql) * HDIM + ks * 16 + 8 * hi);

    f32x16 o0, o1;
#pragma unroll
    for (int r = 0; r < 16; r++) { o0[r] = 0.f; o1[r] = 0.f; }
    float mx = -1e30f, lsum = 0.f;  // per-lane state for q = qrow + ql

    // prologue: stage chunk 0 (keys 0..127) into buf 0
#pragma unroll
    for (int i = 0; i < 4; i++) gload16(kS[i], kD + i * 4096);
#pragma unroll
    for (int hh = 0; hh < 2; hh++)
#pragma unroll
        for (int i = 0; i < 2; i++)
            gload16(vS[i] + 64 * hh, vD + hh * 8192 + i * 4096);
    __syncthreads();

    for (int c = 0; c < ncAll; c++) {
        int c0 = c * 128;
        if (c + 1 < ncAll) {
            int nb = (c + 1) & 1;
            int cn = c0 + 128;
#pragma unroll
            for (int i = 0; i < 4; i++)
                gload16(kS[i] + (size_t)cn * HDIM, kD + nb * 16384 + i * 4096);
#pragma unroll
            for (int hh = 0; hh < 2; hh++)
#pragma unroll
                for (int i = 0; i < 2; i++)
                    gload16(vS[i] + cn + 64 * hh,
                            vD + nb * 16384 + hh * 8192 + i * 4096);
        }

        if (c < myNc) {
            const char* kb_ = (const char*)&sK[c & 1][0];

            // ---- QK^T swapped: st[kg] keys kg*32.., cols = q (per-lane) ----
            f32x16 st[4];
#pragma unroll
            for (int kg = 0; kg < 4; kg++)
#pragma unroll
                for (int r = 0; r < 16; r++) st[kg][r] = 0.f;
#pragma unroll
            for (int ks = 0; ks < 4; ks++) {
                int so = ((2 * ks + hi) ^ (ql & 7)) << 4;
#pragma unroll
                for (int kg = 0; kg < 4; kg++) {
                    bf16x8 kA = *reinterpret_cast<const bf16x8*>(
                        kb_ + (kg * 32 + ql) * 128 + so);
                    st[kg] = MFMA32(kA, qf[ks], st[kg]);
                }
            }

            if (c == myNc - 1) {  // diagonal chunk: causal mask (key > q)
#pragma unroll
                for (int kg = 0; kg < 4; kg++)
#pragma unroll
                    for (int r = 0; r < 16; r++) {
                        int kl = c0 + kg * 32 + (r & 3) + 8 * (r >> 2) + 4 * hi;
                        if (kl > qrow + ql) st[kg][r] = -1e30f;
                    }
            }

            // ---- softmax: per-lane row (q = ql), exp2 domain, defer-max ----
            float pmax = -1e30f;
#pragma unroll
            for (int kg = 0; kg < 4; kg++)
#pragma unroll
                for (int r = 0; r < 16; r++) pmax = fmaxf(pmax, st[kg][r]);
            pmax = xhalf_max(pmax);
            float mxold = mx;
            bool defer = (pmax <= mxold + 8.0f);
            float mn = defer ? mxold : fmaxf(mxold, pmax);
            mx = mn;
            float ps = 0.f;
#pragma unroll
            for (int kg = 0; kg < 4; kg++)
#pragma unroll
                for (int r = 0; r < 16; r++) {
                    st[kg][r] = __builtin_amdgcn_exp2f(st[kg][r] - mn);
                    ps += st[kg][r];
                }
            ps = xhalf_sum(ps);
            if (!__all(defer)) {
                float scl = __builtin_amdgcn_exp2f(mxold - mn);  // 1 on defer lanes
                lsum = lsum * scl + ps;
#pragma unroll
                for (int r = 0; r < 16; r++) { o0[r] *= scl; o1[r] *= scl; }
            } else {
                lsum += ps;
            }

            // ---- PV swapped, P B-frags built in-register ----
#pragma unroll
            for (int kg = 0; kg < 4; kg++) {
                f32x16 P = st[kg];
#pragma unroll
                for (int sub = 0; sub < 2; sub++) {
                    int ks8 = 2 * kg + sub;
                    int bs = 8 * sub;
                    unsigned X0 = pkbf(P[bs + 0], P[bs + 1]);
                    unsigned X1 = pkbf(P[bs + 2], P[bs + 3]);
                    unsigned Y0 = pkbf(P[bs + 4], P[bs + 5]);
                    unsigned Y1 = pkbf(P[bs + 6], P[bs + 7]);
                    uint2v s0 = __builtin_amdgcn_permlane32_swap(X0, Y0, false, false);
                    uint2v s1 = __builtin_amdgcn_permlane32_swap(X1, Y1, false, false);
                    uint4v uw;
                    uw[0] = s0[0];
                    uw[1] = s1[0];
                    uw[2] = s0[1];
                    uw[3] = s1[1];
                    bf16x8 pb = __builtin_bit_cast(bf16x8, uw);
                    const char* vb_ = (const char*)&sV[c & 1][ks8 >> 2][0];
                    int kss = ks8 & 3;
                    int so = ((2 * kss + hi) ^ (ql & 7)) << 4;
                    bf16x8 vA0 = *reinterpret_cast<const bf16x8*>(vb_ + ql * 128 + so);
                    bf16x8 vA1 = *reinterpret_cast<const bf16x8*>(vb_ + (32 + ql) * 128 + so);
                    o0 = MFMA32(vA0, pb, o0);
                    o1 = MFMA32(vA1, pb, o1);
                }
            }
        }

        __syncthreads();  // drain staging vmcnt; all waves done with buf
    }

    // ---- epilogue: per-lane normalize; q = qrow+ql, d = 8j+4hi+e (+32) ----
    float inv = 1.f / lsum;
    size_t base = ((size_t)b_ * SEQ + qrow + ql) * EMB + h_ * HDIM;
#pragma unroll
    for (int j = 0; j < 4; j++) {
        bf16x4 w0, w1;
#pragma unroll
        for (int e = 0; e < 4; e++) {
            w0[e] = (bf16)(o0[4 * j + e] * inv);
            w1[e] = (bf16)(o1[4 * j + e] * inv);
        }
        *reinterpret_cast<bf16x4*>(ctx + base + 8 * j + 4 * hi) = w0;
        *reinterpret_cast<bf16x4*>(ctx + base + 32 + 8 * j + 4 * hi) = w1;
    }
}

// ---------------- launch ---------------------------------------------------
extern "C" void kernel_launch(void* const* d_in, const int* in_sizes, int n_in,
                              void* d_out, int out_size, void* d_ws, size_t ws_size,
                              hipStream_t stream) {
    const float* x  = (const float*)d_in[0];
    const float* Wq = (const float*)d_in[1];
    const float* Wk = (const float*)d_in[2];
    const float* Wv = (const float*)d_in[3];
    const float* Wo = (const float*)d_in[4];
    const float* bo = (const float*)d_in[5];
    const float* W1 = (const float*)d_in[6];
    const float* b1 = (const float*)d_in[7];
    const float* W2 = (const float*)d_in[8];
    const float* b2 = (const float*)d_in[9];
    const float* g1 = (const float*)d_in[10];
    const float* s1 = (const float*)d_in[11];
    const float* g2 = (const float*)d_in[12];
    const float* s2 = (const float*)d_in[13];

    const size_t MB = 1ull << 20;
    char* w = (char*)d_ws;
    bf16* Wqkvt = (bf16*)(w + 0 * MB);            // [3072][1024], dead after QKV
    bf16* Wot = (bf16*)(w + 6 * MB);              // dead after Wo
    bf16* W1t = (bf16*)(w + 8 * MB);              // dead after FFN1
    bf16* W2t = (bf16*)(w + 16 * MB);             // live till FFN2
    bf16* hbuf = (bf16*)(w + 24 * MB);            // h1 / h2, dead after FFN1
    bf16* vtb  = (bf16*)(w + 24 * MB);            // aliases hbuf (QKV..attn window)
    bf16* qkvb = (bf16*)(w + 32 * MB);            // q/k/v, dead after attn
    bf16* qb   = (bf16*)(w + 32 * MB);
    bf16* kb   = (bf16*)(w + 40 * MB);
    bf16* vb   = (bf16*)(w + 48 * MB);
    bf16* ctxb = (bf16*)(w + 56 * MB);            // dead after Wo
    bf16* midb = (bf16*)(w + 32 * MB);            // 32-64, over dead qkv/ctx
    float* x1  = (float*)(w + 64 * MB);           // live till ffn2_reduce
    bf16* p01  = (bf16*)(w + 0 * MB);             // FFN2 partials z0,z1 (16 MB)
    bf16* p2   = (bf16*)(w + 24 * MB);            // partial z2 (8 MB, dead hbuf)

    // allow 128 KiB dynamic LDS for the 8-phase GEMMs
    hipFuncSetAttribute(reinterpret_cast<const void*>(gemm8p<0>),
                        hipFuncAttributeMaxDynamicSharedMemorySize, 131072);
    hipFuncSetAttribute(reinterpret_cast<const void*>(gemm8p<2>),
                        hipFuncAttributeMaxDynamicSharedMemorySize, 131072);
    hipFuncSetAttribute(reinterpret_cast<const void*>(gemm8p<3>),
                        hipFuncAttributeMaxDynamicSharedMemorySize, 131072);

    // all 6 weight transposes in one dispatch (fp32 -> bf16 [N][K])
    transpose_all<<<dim3(12288), 256, 0, stream>>>(Wq, Wk, Wv, Wo, W1, W2,
                                                   Wqkvt, Wot, W1t, W2t);

    // LN1
    ln_kernel<<<NTOK, 256, 0, stream>>>(x, g1, s1, hbuf);

    // fused QKV projection: [4096,1024] @ [3072,1024]^T  (8-phase 256^2 + T1)
    gemm8p<0><<<dim3(NTOK / 256, 3072 / 256), 512, 131072, stream>>>(
        hbuf, Wqkvt, EMB, 3072, qkvb, nullptr, nullptr);

    // V -> V^T  [B,H,64,S]
    vtrans<<<dim3(SEQ / 64, BATCH * HEADS), 256, 0, stream>>>(vb, vtb);

    // attention (v12b: KVBLK=128)
    attn_kernel<<<dim3(512), 256, 0, stream>>>(qb, kb, vtb, ctxb);

    // output projection + residual -> x1 (f32)  (m97 128x64 + T1)
    gemm_lds<128, 64, 32, 1><<<dim3(NTOK / 128, EMB / 64), 256, 0, stream>>>(
        ctxb, Wot, NTOK, EMB, EMB, x1, nullptr, bo, x);

    // LN2
    ln_kernel<<<NTOK, 256, 0, stream>>>(x1, g2, s2, hbuf);

    // FFN1 + gelu -> bf16 mid  (8-phase 256^2 + T1)
    gemm8p<2><<<dim3(NTOK / 256, FFN / 256), 512, 131072, stream>>>(
        hbuf, W1t, EMB, FFN, midb, nullptr, b1);

    // FFN2 split-K=3 (8-phase 256^2 + T1, bf16 partials) + reduce
    gemm8p<3><<<dim3(NTOK / 256, EMB / 256, 3), 512, 131072, stream>>>(
        midb, W2t, FFN, EMB, p01, p2, nullptr);
    ffn2_reduce<<<dim3(2048), 256, 0, stream>>>(x1, p01, p2, b2, (float*)d_out);
}

// Round 21
// 228.007 us; speedup vs baseline: 1.0100x; 1.0100x over previous
//
#include <hip/hip_runtime.h>
#include <hip/hip_bf16.h>
#include <math.h>
#include <stdint.h>

typedef __bf16 bf16;
typedef __bf16 bf16x2 __attribute__((ext_vector_type(2)));
typedef __bf16 bf16x4 __attribute__((ext_vector_type(4)));
typedef __bf16 bf16x8 __attribute__((ext_vector_type(8)));
typedef float f32x4 __attribute__((ext_vector_type(4)));
typedef float f32x16 __attribute__((ext_vector_type(16)));
typedef unsigned uint2v __attribute__((ext_vector_type(2)));
typedef unsigned uint4v __attribute__((ext_vector_type(4)));

#define MFMA16(a, b, c) __builtin_amdgcn_mfma_f32_16x16x32_bf16((a), (b), (c), 0, 0, 0)
#define MFMA32(a, b, c) __builtin_amdgcn_mfma_f32_32x32x16_bf16((a), (b), (c), 0, 0, 0)

constexpr int EMB = 1024;
constexpr int SEQ = 2048;
constexpr int BATCH = 2;
constexpr int NTOK = BATCH * SEQ;   // 4096
constexpr int FFN = 4 * EMB;        // 4096
constexpr int HEADS = 16;
constexpr int HDIM = 64;

// q pre-scale: 1/sqrt(64) * log2(e)  (softmax runs in exp2 domain)
#define QSCALE 0.18033688011112042f

// async 16B global -> LDS (wave-uniform base + lane*16 destination)
__device__ __forceinline__ void gload16(const void* g, void* l) {
    __builtin_amdgcn_global_load_lds(
        (const __attribute__((address_space(1))) void*)g,
        (__attribute__((address_space(3))) void*)l,
        16, 0, 0);
}

// cross-half (lane i <-> lane i+32) max/sum via v_permlane32_swap (VALU pipe)
__device__ __forceinline__ float xhalf_max(float x) {
    unsigned u = __float_as_uint(x);
    uint2v r = __builtin_amdgcn_permlane32_swap(u, u, false, false);
    return fmaxf(__uint_as_float(r[0]), __uint_as_float(r[1]));
}
__device__ __forceinline__ float xhalf_sum(float x) {
    unsigned u = __float_as_uint(x);
    uint2v r = __builtin_amdgcn_permlane32_swap(u, u, false, false);
    return __uint_as_float(r[0]) + __uint_as_float(r[1]);
}

__device__ __forceinline__ unsigned pkbf(float a, float b) {
    bf16x2 v;
    v[0] = (bf16)a;
    v[1] = (bf16)b;
    return __builtin_bit_cast(unsigned, v);
}

// gelu_tanh(u) = u * sigmoid(2w), w = c*(u + 0.044715 u^3); exp2 domain
__device__ __forceinline__ float gelu_f(float u) {
    float w_ = 0.7978845608028654f * (u + 0.044715f * u * u * u);
    float z = __builtin_amdgcn_exp2f(-2.8853900817779268f * w_);
    return u / (1.f + z);
}

// ---------------- LayerNorm: fp32 in -> bf16 out --------------------------
__global__ __launch_bounds__(256) void ln_kernel(const float* __restrict__ x,
                                                 const float* __restrict__ g,
                                                 const float* __restrict__ b,
                                                 bf16* __restrict__ out) {
    int row = blockIdx.x;
    int t = threadIdx.x;
    float4 v = reinterpret_cast<const float4*>(x + (size_t)row * EMB)[t];
    float s = v.x + v.y + v.z + v.w;
    float s2 = v.x * v.x + v.y * v.y + v.z * v.z + v.w * v.w;
#pragma unroll
    for (int o = 1; o < 64; o <<= 1) {
        s += __shfl_xor(s, o);
        s2 += __shfl_xor(s2, o);
    }
    __shared__ float ps[4], ps2[4];
    int w = t >> 6;
    if ((t & 63) == 0) { ps[w] = s; ps2[w] = s2; }
    __syncthreads();
    s = ps[0] + ps[1] + ps[2] + ps[3];
    s2 = ps2[0] + ps2[1] + ps2[2] + ps2[3];
    float mean = s * (1.f / EMB);
    float var = s2 * (1.f / EMB) - mean * mean;
    float rstd = rsqrtf(var + 1e-5f);
    float4 gv = reinterpret_cast<const float4*>(g)[t];
    float4 bv = reinterpret_cast<const float4*>(b)[t];
    bf16* op = out + (size_t)row * EMB + t * 4;
    op[0] = (bf16)(gv.x * (v.x - mean) * rstd + bv.x);
    op[1] = (bf16)(gv.y * (v.y - mean) * rstd + bv.y);
    op[2] = (bf16)(gv.z * (v.z - mean) * rstd + bv.z);
    op[3] = (bf16)(gv.w * (v.w - mean) * rstd + bv.w);
}

// ---- fused transpose + cast: all 6 weights, W[K][N] f32 -> Wt[N][K] bf16 --
__global__ __launch_bounds__(256) void transpose_all(
    const float* __restrict__ Wq, const float* __restrict__ Wk,
    const float* __restrict__ Wv, const float* __restrict__ Wo,
    const float* __restrict__ W1, const float* __restrict__ W2,
    bf16* __restrict__ Wqkvt, bf16* __restrict__ Wot,
    bf16* __restrict__ W1t, bf16* __restrict__ W2t) {
    int b = blockIdx.x;
    const float* W;
    bf16* Wt;
    int K, N, tile;
    if (b < 4096) {
        int w = b >> 10;
        tile = b & 1023;
        W = (w == 0) ? Wq : (w == 1) ? Wk : (w == 2) ? Wv : Wo;
        Wt = (w == 3) ? Wot : Wqkvt + (size_t)w * EMB * EMB;
        K = EMB; N = EMB;
    } else if (b < 8192) {
        tile = b - 4096; W = W1; Wt = W1t; K = EMB; N = FFN;
    } else {
        tile = b - 8192; W = W2; Wt = W2t; K = FFN; N = EMB;
    }
    int ntx = N / 32;
    int n0 = (tile % ntx) * 32, k0 = (tile / ntx) * 32;
    __shared__ float tl[32][33];
    int tx = threadIdx.x & 31, ty = threadIdx.x >> 5;  // 32 x 8
#pragma unroll
    for (int i = 0; i < 4; i++)
        tl[ty + 8 * i][tx] = W[(size_t)(k0 + ty + 8 * i) * N + n0 + tx];
    __syncthreads();
#pragma unroll
    for (int i = 0; i < 4; i++)
        Wt[(size_t)(n0 + ty + 8 * i) * K + k0 + tx] = (bf16)tl[tx][ty + 8 * i];
}

// ---------------- V transpose: [B,H,S,64] -> [B,H,64,S] bf16 --------------
__global__ __launch_bounds__(256) void vtrans(const bf16* __restrict__ v,
                                              bf16* __restrict__ vt) {
    int bh = blockIdx.y;
    int s0 = blockIdx.x * 64;
    const bf16* src = v + (size_t)bh * SEQ * HDIM + (size_t)s0 * HDIM;
    bf16* dst = vt + (size_t)bh * HDIM * SEQ + s0;
    __shared__ bf16 tile[64][72];
    int t = threadIdx.x;
    int s = t >> 2, d0 = (t & 3) * 16;
    bf16x8 a = *reinterpret_cast<const bf16x8*>(src + s * HDIM + d0);
    bf16x8 b = *reinterpret_cast<const bf16x8*>(src + s * HDIM + d0 + 8);
#pragma unroll
    for (int e = 0; e < 8; e++) {
        tile[d0 + e][s] = a[e];
        tile[d0 + 8 + e][s] = b[e];
    }
    __syncthreads();
    int d = t >> 2, c0 = (t & 3) * 16;
    bf16x8 o0 = *reinterpret_cast<const bf16x8*>(&tile[d][c0]);
    bf16x8 o1 = *reinterpret_cast<const bf16x8*>(&tile[d][c0 + 8]);
    *reinterpret_cast<bf16x8*>(dst + (size_t)d * SEQ + c0) = o0;
    *reinterpret_cast<bf16x8*>(dst + (size_t)d * SEQ + c0 + 8) = o1;
}

// ---------------- 8-phase 256x256 GEMM, counted-vmcnt (T2+T3+T4+T5) -------
// MODE 0: fused QKV scatter -> bf16 q/k/v [B,H,S,64] (q scaled QSCALE)
// MODE 2: out bf16 = gelu(acc + bias)
// MODE 3: bf16 partial tile -> z<2: outB + z*NTOK*EMB ; z==2: outB2
template <int MODE>
__global__ __launch_bounds__(512, 1) void gemm8p(const bf16* __restrict__ A,
                                                 const bf16* __restrict__ Bt,
                                                 int K, int N,
                                                 bf16* __restrict__ outB,
                                                 bf16* __restrict__ outB2,
                                                 const float* __restrict__ bias) {
    extern __shared__ char smem[];  // [buf][A 32K | B 32K] x2 = 128 KiB
    int t = threadIdx.x;
    int wave = t >> 6, lane = t & 63;
    int wr = wave >> 2, wc = wave & 3;      // 2 x 4 wave grid
    int lr = lane & 15, lg = lane >> 4;
    int row0 = blockIdx.x * 256;
    int col0 = blockIdx.y * 256;

    int tilesAll = K / 64;
    int nz = gridDim.z, z = blockIdx.z;
    int base = tilesAll / nz, rem = tilesAll - base * nz;
    int myT = base + (z < rem ? 1 : 0);
    int tBeg = z * base + (z < rem ? z : rem);

    const char* aSrc[4];
    const char* bSrc[4];
#pragma unroll
    for (int i = 0; i < 4; i++) {
        int f = t + i * 512;
        int gr = f >> 3, gk = f & 7;
        aSrc[i] = (const char*)A + ((size_t)(row0 + gr) * K + ((gk ^ (gr & 7)) << 3)) * 2
                  + (size_t)tBeg * 128;
        bSrc[i] = (const char*)Bt + ((size_t)(col0 + gr) * K + ((gk ^ (gr & 7)) << 3)) * 2
                  + (size_t)tBeg * 128;
    }

    f32x4 acc[8][4];
#pragma unroll
    for (int m = 0; m < 8; m++)
#pragma unroll
        for (int n = 0; n < 4; n++) acc[m][n] = f32x4{0.f, 0.f, 0.f, 0.f};

    // prologue: stage tile 0 into buf 0; issue order B0,B1,B2,B3,A0,A2,A1,A3
    gload16(bSrc[0], smem + 32768 + (t + 0 * 512) * 16);
    gload16(bSrc[1], smem + 32768 + (t + 1 * 512) * 16);
    gload16(bSrc[2], smem + 32768 + (t + 2 * 512) * 16);
    gload16(bSrc[3], smem + 32768 + (t + 3 * 512) * 16);
    gload16(aSrc[0], smem + (t + 0 * 512) * 16);
    gload16(aSrc[2], smem + (t + 2 * 512) * 16);
    gload16(aSrc[1], smem + (t + 1 * 512) * 16);
    gload16(aSrc[3], smem + (t + 3 * 512) * 16);
    asm volatile("s_waitcnt vmcnt(2)" ::: "memory");
    __builtin_amdgcn_s_barrier();

    for (int tk = 0; tk < myT; tk++) {
        int cur = tk & 1;
        const char* la = smem + cur * 65536;
        const char* lb = la + 32768;
        char* na = smem + (cur ^ 1) * 65536;
        bool stage = (tk + 1 < myT);

        bf16x8 bfr[2][4];
#pragma unroll
        for (int ph = 0; ph < 4; ph++) {
            constexpr int PH_KH[4] = {0, 0, 1, 1};
            constexpr int PH_MH[4] = {0, 1, 0, 1};
            const int kh = PH_KH[ph], mh = PH_MH[ph];
            bf16x8 afr[4];
#pragma unroll
            for (int m = 0; m < 4; m++) {
                int row = wr * 128 + (mh * 4 + m) * 16 + lr;
                int gk = kh * 4 + lg;
                afr[m] = *reinterpret_cast<const bf16x8*>(
                    la + row * 128 + ((gk ^ (row & 7)) << 4));
            }
            if (mh == 0) {
#pragma unroll
                for (int n = 0; n < 4; n++) {
                    int row = wc * 64 + n * 16 + lr;
                    int gk = kh * 4 + lg;
                    bfr[kh][n] = *reinterpret_cast<const bf16x8*>(
                        lb + row * 128 + ((gk ^ (row & 7)) << 4));
                }
            }
            if (stage) {
                if (ph == 0) {
                    gload16(bSrc[0] + 128, na + 32768 + (t + 0 * 512) * 16);
                    gload16(bSrc[1] + 128, na + 32768 + (t + 1 * 512) * 16);
                } else if (ph == 1) {
                    gload16(bSrc[2] + 128, na + 32768 + (t + 2 * 512) * 16);
                    gload16(bSrc[3] + 128, na + 32768 + (t + 3 * 512) * 16);
                } else if (ph == 2) {
                    gload16(aSrc[0] + 128, na + (t + 0 * 512) * 16);
                    gload16(aSrc[2] + 128, na + (t + 2 * 512) * 16);
                } else {
                    gload16(aSrc[1] + 128, na + (t + 1 * 512) * 16);
                    gload16(aSrc[3] + 128, na + (t + 3 * 512) * 16);
                }
            }
            __builtin_amdgcn_s_barrier();
            __builtin_amdgcn_s_setprio(1);
#pragma unroll
            for (int m = 0; m < 4; m++)
#pragma unroll
                for (int n = 0; n < 4; n++)
                    acc[mh * 4 + m][n] = MFMA16(afr[m], bfr[kh][n], acc[mh * 4 + m][n]);
            __builtin_amdgcn_s_setprio(0);
            if (ph == 0 || ph == 3)
                asm volatile("s_waitcnt vmcnt(2)" ::: "memory");
            __builtin_amdgcn_s_barrier();
        }
#pragma unroll
        for (int i = 0; i < 4; i++) { aSrc[i] += 128; bSrc[i] += 128; }
    }

    float bi[4];
    if (MODE == 2) {
#pragma unroll
        for (int n = 0; n < 4; n++) bi[n] = bias[col0 + wc * 64 + n * 16 + lr];
    }
    bf16* pd = outB;
    if (MODE == 3) pd = (z < 2) ? outB + (size_t)z * ((size_t)NTOK * EMB) : outB2;
#pragma unroll
    for (int mf = 0; mf < 8; mf++) {
#pragma unroll
        for (int r = 0; r < 4; r++) {
            int row = row0 + wr * 128 + mf * 16 + 4 * lg + r;
#pragma unroll
            for (int n = 0; n < 4; n++) {
                int col = col0 + wc * 64 + n * 16 + lr;
                float v = acc[mf][n][r];
                if (MODE == 0) {
                    int b_ = row >> 11, s_ = row & 2047;
                    int which = col >> 10, rem_ = col & 1023;
                    int h_ = rem_ >> 6, d_ = rem_ & 63;
                    float sc = (which == 0) ? QSCALE : 1.0f;
                    outB[(size_t)which * (NTOK * EMB) +
                         (((size_t)(b_ * HEADS + h_) * SEQ + s_) << 6) + d_] =
                        (bf16)(v * sc);
                } else if (MODE == 2) {
                    outB[(size_t)row * N + col] = (bf16)gelu_f(v + bi[n]);
                } else {
                    pd[(size_t)row * N + col] = (bf16)v;
                }
            }
        }
    }
}

// ------- FFN2 reduce: out = x1 + p0 + p1 + p2 + bias (all fp32 out) -------
__global__ __launch_bounds__(256) void ffn2_reduce(const float* __restrict__ x1,
                                                   const bf16* __restrict__ p01,
                                                   const bf16* __restrict__ p2,
                                                   const float* __restrict__ bias,
                                                   float* __restrict__ out) {
    constexpr int UNITS = NTOK * EMB / 4;
    const bf16* p1 = p01 + (size_t)NTOK * EMB;
    for (int i = blockIdx.x * 256 + threadIdx.x; i < UNITS; i += gridDim.x * 256) {
        float4 r = reinterpret_cast<const float4*>(x1)[i];
        float4 bv = reinterpret_cast<const float4*>(bias)[i & (EMB / 4 - 1)];
        bf16x4 a0 = reinterpret_cast<const bf16x4*>(p01)[i];
        bf16x4 a1 = reinterpret_cast<const bf16x4*>(p1)[i];
        bf16x4 a2 = reinterpret_cast<const bf16x4*>(p2)[i];
        r.x += (float)a0[0] + (float)a1[0] + (float)a2[0] + bv.x;
        r.y += (float)a0[1] + (float)a1[1] + (float)a2[1] + bv.y;
        r.z += (float)a0[2] + (float)a1[2] + (float)a2[2] + bv.z;
        r.w += (float)a0[3] + (float)a1[3] + (float)a2[3] + bv.w;
        reinterpret_cast<float4*>(out)[i] = r;
    }
}

// ---------------- LDS-staged GEMM (m97 structure) -------------------------
// MODE 1: out f32 = resid + acc + bias
template <int BM, int BN, int BK, int MODE>
__global__ __launch_bounds__(256) void gemm_lds(const bf16* __restrict__ A,
                                                const bf16* __restrict__ Bt,
                                                int M, int N, int K,
                                                float* __restrict__ outF,
                                                bf16* __restrict__ outB,
                                                const float* __restrict__ bias,
                                                const float* __restrict__ resid) {
    constexpr int MR = BM / 32;
    constexpr int NR = BN / 32;
    constexpr int ACH = (BM * BK * 2) / 4096;
    constexpr int BCH = (BN * BK * 2) / 4096;
    __shared__ bf16 sA[BM * BK];
    __shared__ bf16 sB[BN * BK];
    int t = threadIdx.x;
    int wave = t >> 6, lane = t & 63;
    int wr = wave >> 1, wc = wave & 1;
    int lr = lane & 15, lg = lane >> 4;
    int row0 = blockIdx.x * BM;
    int col0 = blockIdx.y * BN;

    const char* aS[ACH];
    const char* bS[BCH];
#pragma unroll
    for (int c = 0; c < ACH; c++) {
        int o = (t + c * 256) * 16;
        aS[c] = (const char*)A + (size_t)(row0 + o / (2 * BK)) * K * 2 + (o & (2 * BK - 1));
    }
#pragma unroll
    for (int c = 0; c < BCH; c++) {
        int o = (t + c * 256) * 16;
        bS[c] = (const char*)Bt + (size_t)(col0 + o / (2 * BK)) * K * 2 + (o & (2 * BK - 1));
    }

    f32x4 acc[MR][NR];
#pragma unroll
    for (int m = 0; m < MR; m++)
#pragma unroll
        for (int n = 0; n < NR; n++) acc[m][n] = f32x4{0.f, 0.f, 0.f, 0.f};

    for (int k0 = 0; k0 < K; k0 += BK) {
        __syncthreads();
#pragma unroll
        for (int c = 0; c < ACH; c++)
            gload16(aS[c], (char*)sA + (t + c * 256) * 16);
#pragma unroll
        for (int c = 0; c < BCH; c++)
            gload16(bS[c], (char*)sB + (t + c * 256) * 16);
#pragma unroll
        for (int c = 0; c < ACH; c++) aS[c] += 2 * BK;
#pragma unroll
        for (int c = 0; c < BCH; c++) bS[c] += 2 * BK;
        __syncthreads();

#pragma unroll
        for (int ks = 0; ks < BK / 32; ks++) {
            bf16x8 a[MR], b[NR];
#pragma unroll
            for (int m = 0; m < MR; m++)
                a[m] = *reinterpret_cast<const bf16x8*>(
                    sA + (wr * (BM / 2) + m * 16 + lr) * BK + ks * 32 + 8 * lg);
#pragma unroll
            for (int n = 0; n < NR; n++)
                b[n] = *reinterpret_cast<const bf16x8*>(
                    sB + (wc * (BN / 2) + n * 16 + lr) * BK + ks * 32 + 8 * lg);
#pragma unroll
            for (int m = 0; m < MR; m++)
#pragma unroll
                for (int n = 0; n < NR; n++)
                    acc[m][n] = MFMA16(a[m], b[n], acc[m][n]);
        }
    }

#pragma unroll
    for (int m = 0; m < MR; m++) {
#pragma unroll
        for (int r = 0; r < 4; r++) {
            int row = row0 + wr * (BM / 2) + m * 16 + 4 * lg + r;
#pragma unroll
            for (int n = 0; n < NR; n++) {
                int col = col0 + wc * (BN / 2) + n * 16 + lr;
                float v = acc[m][n][r];
                size_t idx = (size_t)row * N + col;
                outF[idx] = resid[idx] + v + bias[col];
            }
        }
    }
}

// ---------------- causal flash attention (v12b: KVBLK=128) -----------------
__global__ __launch_bounds__(256, 2) void attn_kernel(const bf16* __restrict__ q,
                                                      const bf16* __restrict__ k,
                                                      const bf16* __restrict__ vt,
                                                      bf16* __restrict__ ctx) {
    int wg = blockIdx.x;
    int wgid = (wg & 7) * 64 + (wg >> 3);   // bijective: 512 = 8 XCD * 64
    int bh = wgid >> 4;                     // 16 blocks/head, 4 heads/XCD
    int pair = wgid & 15;
    const bf16* qh = q + (size_t)bh * SEQ * HDIM;
    const bf16* kh = k + (size_t)bh * SEQ * HDIM;
    const bf16* vh = vt + (size_t)bh * HDIM * SEQ;  // [64][2048]
    int t = threadIdx.x;
    int wave = t >> 6, lane = t & 63;
    int ql = lane & 31, hi = lane >> 5;

    int s64 = (wave < 2) ? (31 - pair) : pair;   // q-span in 64-row units
    int qrow = s64 * 64 + (wave & 1) * 32;
    int myNc = (s64 >> 1) + 1;                   // 128-key chunks this wave needs
    int ncAll = ((31 - pair) >> 1) + 1;          // chunks staged (heavy range)

    __shared__ bf16 sK[2][128 * 64];     // [key][d], granule-swizzled (16 KB/buf)
    __shared__ bf16 sV[2][2][64 * 64];   // [half][d][key], granule-swizzled

    int grow = t >> 3, gg = t & 7;
    const bf16* kS[4];
#pragma unroll
    for (int i = 0; i < 4; i++)
        kS[i] = kh + (size_t)(grow + 32 * i) * HDIM + ((gg ^ ((grow + 32 * i) & 7)) << 3);
    const bf16* vS[2];
#pragma unroll
    for (int i = 0; i < 2; i++)
        vS[i] = vh + (size_t)(grow + 32 * i) * SEQ + ((gg ^ ((grow + 32 * i) & 7)) << 3);
    char* kD = (char*)&sK[0][0] + wave * 1024;
    char* vD = (char*)&sV[0][0][0] + wave * 1024;

    int b_ = bh >> 4, h_ = bh & 15;

    // Q fragments (B-operand): col=q=ql, k = 8*hi+e over d-slices ks*16
    bf16x8 qf[4];
#pragma unroll
    for (int ks = 0; ks < 4; ks++)
        qf[ks] = *reinterpret_cast<const bf16x8*>(
            qh + (size_t)(qrow + ql) * HDIM + ks * 16 + 8 * hi);

    f32x16 o0, o1;
#pragma unroll
    for (int r = 0; r < 16; r++) { o0[r] = 0.f; o1[r] = 0.f; }
    float mx = -1e30f, lsum = 0.f;  // per-lane state for q = qrow + ql

    // prologue: stage chunk 0 (keys 0..127) into buf 0
#pragma unroll
    for (int i = 0; i < 4; i++) gload16(kS[i], kD + i * 4096);
#pragma unroll
    for (int hh = 0; hh < 2; hh++)
#pragma unroll
        for (int i = 0; i < 2; i++)
            gload16(vS[i] + 64 * hh, vD + hh * 8192 + i * 4096);
    __syncthreads();

    for (int c = 0; c < ncAll; c++) {
        int c0 = c * 128;
        if (c + 1 < ncAll) {
            int nb = (c + 1) & 1;
            int cn = c0 + 128;
#pragma unroll
            for (int i = 0; i < 4; i++)
                gload16(kS[i] + (size_t)cn * HDIM, kD + nb * 16384 + i * 4096);
#pragma unroll
            for (int hh = 0; hh < 2; hh++)
#pragma unroll
                for (int i = 0; i < 2; i++)
                    gload16(vS[i] + cn + 64 * hh,
                            vD + nb * 16384 + hh * 8192 + i * 4096);
        }

        if (c < myNc) {
            const char* kb_ = (const char*)&sK[c & 1][0];

            // ---- QK^T swapped: st[kg] keys kg*32.., cols = q (per-lane) ----
            f32x16 st[4];
#pragma unroll
            for (int kg = 0; kg < 4; kg++)
#pragma unroll
                for (int r = 0; r < 16; r++) st[kg][r] = 0.f;
#pragma unroll
            for (int ks = 0; ks < 4; ks++) {
                int so = ((2 * ks + hi) ^ (ql & 7)) << 4;
#pragma unroll
                for (int kg = 0; kg < 4; kg++) {
                    bf16x8 kA = *reinterpret_cast<const bf16x8*>(
                        kb_ + (kg * 32 + ql) * 128 + so);
                    st[kg] = MFMA32(kA, qf[ks], st[kg]);
                }
            }

            if (c == myNc - 1) {  // diagonal chunk: causal mask (key > q)
#pragma unroll
                for (int kg = 0; kg < 4; kg++)
#pragma unroll
                    for (int r = 0; r < 16; r++) {
                        int kl = c0 + kg * 32 + (r & 3) + 8 * (r >> 2) + 4 * hi;
                        if (kl > qrow + ql) st[kg][r] = -1e30f;
                    }
            }

            // ---- softmax: per-lane row (q = ql), exp2 domain, defer-max ----
            float pmax = -1e30f;
#pragma unroll
            for (int kg = 0; kg < 4; kg++)
#pragma unroll
                for (int r = 0; r < 16; r++) pmax = fmaxf(pmax, st[kg][r]);
            pmax = xhalf_max(pmax);
            float mxold = mx;
            bool defer = (pmax <= mxold + 8.0f);
            float mn = defer ? mxold : fmaxf(mxold, pmax);
            mx = mn;
            float ps = 0.f;
#pragma unroll
            for (int kg = 0; kg < 4; kg++)
#pragma unroll
                for (int r = 0; r < 16; r++) {
                    st[kg][r] = __builtin_amdgcn_exp2f(st[kg][r] - mn);
                    ps += st[kg][r];
                }
            ps = xhalf_sum(ps);
            if (!__all(defer)) {
                float scl = __builtin_amdgcn_exp2f(mxold - mn);  // 1 on defer lanes
                lsum = lsum * scl + ps;
#pragma unroll
                for (int r = 0; r < 16; r++) { o0[r] *= scl; o1[r] *= scl; }
            } else {
                lsum += ps;
            }

            // ---- PV swapped, P B-frags built in-register ----
#pragma unroll
            for (int kg = 0; kg < 4; kg++) {
                f32x16 P = st[kg];
#pragma unroll
                for (int sub = 0; sub < 2; sub++) {
                    int ks8 = 2 * kg + sub;
                    int bs = 8 * sub;
                    unsigned X0 = pkbf(P[bs + 0], P[bs + 1]);
                    unsigned X1 = pkbf(P[bs + 2], P[bs + 3]);
                    unsigned Y0 = pkbf(P[bs + 4], P[bs + 5]);
                    unsigned Y1 = pkbf(P[bs + 6], P[bs + 7]);
                    uint2v s0 = __builtin_amdgcn_permlane32_swap(X0, Y0, false, false);
                    uint2v s1 = __builtin_amdgcn_permlane32_swap(X1, Y1, false, false);
                    uint4v uw;
                    uw[0] = s0[0];
                    uw[1] = s1[0];
                    uw[2] = s0[1];
                    uw[3] = s1[1];
                    bf16x8 pb = __builtin_bit_cast(bf16x8, uw);
                    const char* vb_ = (const char*)&sV[c & 1][ks8 >> 2][0];
                    int kss = ks8 & 3;
                    int so = ((2 * kss + hi) ^ (ql & 7)) << 4;
                    bf16x8 vA0 = *reinterpret_cast<const bf16x8*>(vb_ + ql * 128 + so);
                    bf16x8 vA1 = *reinterpret_cast<const bf16x8*>(vb_ + (32 + ql) * 128 + so);
                    o0 = MFMA32(vA0, pb, o0);
                    o1 = MFMA32(vA1, pb, o1);
                }
            }
        }

        __syncthreads();  // drain staging vmcnt; all waves done with buf
    }

    // ---- epilogue: per-lane normalize; q = qrow+ql, d = 8j+4hi+e (+32) ----
    float inv = 1.f / lsum;
    size_t base = ((size_t)b_ * SEQ + qrow + ql) * EMB + h_ * HDIM;
#pragma unroll
    for (int j = 0; j < 4; j++) {
        bf16x4 w0, w1;
#pragma unroll
        for (int e = 0; e < 4; e++) {
            w0[e] = (bf16)(o0[4 * j + e] * inv);
            w1[e] = (bf16)(o1[4 * j + e] * inv);
        }
        *reinterpret_cast<bf16x4*>(ctx + base + 8 * j + 4 * hi) = w0;
        *reinterpret_cast<bf16x4*>(ctx + base + 32 + 8 * j + 4 * hi) = w1;
    }
}

// ---------------- launch ---------------------------------------------------
extern "C" void kernel_launch(void* const* d_in, const int* in_sizes, int n_in,
                              void* d_out, int out_size, void* d_ws, size_t ws_size,
                              hipStream_t stream) {
    const float* x  = (const float*)d_in[0];
    const float* Wq = (const float*)d_in[1];
    const float* Wk = (const float*)d_in[2];
    const float* Wv = (const float*)d_in[3];
    const float* Wo = (const float*)d_in[4];
    const float* bo = (const float*)d_in[5];
    const float* W1 = (const float*)d_in[6];
    const float* b1 = (const float*)d_in[7];
    const float* W2 = (const float*)d_in[8];
    const float* b2 = (const float*)d_in[9];
    const float* g1 = (const float*)d_in[10];
    const float* s1 = (const float*)d_in[11];
    const float* g2 = (const float*)d_in[12];
    const float* s2 = (const float*)d_in[13];

    const size_t MB = 1ull << 20;
    char* w = (char*)d_ws;
    bf16* Wqkvt = (bf16*)(w + 0 * MB);            // [3072][1024], dead after QKV
    bf16* Wot = (bf16*)(w + 6 * MB);              // dead after Wo
    bf16* W1t = (bf16*)(w + 8 * MB);              // dead after FFN1
    bf16* W2t = (bf16*)(w + 16 * MB);             // live till FFN2
    bf16* hbuf = (bf16*)(w + 24 * MB);            // h1 / h2, dead after FFN1
    bf16* vtb  = (bf16*)(w + 24 * MB);            // aliases hbuf (QKV..attn window)
    bf16* qkvb = (bf16*)(w + 32 * MB);            // q/k/v, dead after attn
    bf16* qb   = (bf16*)(w + 32 * MB);
    bf16* kb   = (bf16*)(w + 40 * MB);
    bf16* vb   = (bf16*)(w + 48 * MB);
    bf16* ctxb = (bf16*)(w + 56 * MB);            // dead after Wo
    bf16* midb = (bf16*)(w + 32 * MB);            // 32-64, over dead qkv/ctx
    float* x1  = (float*)(w + 64 * MB);           // live till ffn2_reduce
    bf16* p01  = (bf16*)(w + 0 * MB);             // FFN2 partials z0,z1 (16 MB)
    bf16* p2   = (bf16*)(w + 24 * MB);            // partial z2 (8 MB, dead hbuf)

    // allow 128 KiB dynamic LDS for the 8-phase GEMMs
    hipFuncSetAttribute(reinterpret_cast<const void*>(gemm8p<0>),
                        hipFuncAttributeMaxDynamicSharedMemorySize, 131072);
    hipFuncSetAttribute(reinterpret_cast<const void*>(gemm8p<2>),
                        hipFuncAttributeMaxDynamicSharedMemorySize, 131072);
    hipFuncSetAttribute(reinterpret_cast<const void*>(gemm8p<3>),
                        hipFuncAttributeMaxDynamicSharedMemorySize, 131072);

    // all 6 weight transposes in one dispatch (fp32 -> bf16 [N][K])
    transpose_all<<<dim3(12288), 256, 0, stream>>>(Wq, Wk, Wv, Wo, W1, W2,
                                                   Wqkvt, Wot, W1t, W2t);

    // LN1
    ln_kernel<<<NTOK, 256, 0, stream>>>(x, g1, s1, hbuf);

    // fused QKV projection: [4096,1024] @ [3072,1024]^T  (8-phase 256^2)
    gemm8p<0><<<dim3(NTOK / 256, 3072 / 256), 512, 131072, stream>>>(
        hbuf, Wqkvt, EMB, 3072, qkvb, nullptr, nullptr);

    // V -> V^T  [B,H,64,S]
    vtrans<<<dim3(SEQ / 64, BATCH * HEADS), 256, 0, stream>>>(vb, vtb);

    // attention (v12b: KVBLK=128)
    attn_kernel<<<dim3(512), 256, 0, stream>>>(qb, kb, vtb, ctxb);

    // output projection + residual -> x1 (f32)  (m97 128x64, BK=32)
    gemm_lds<128, 64, 32, 1><<<dim3(NTOK / 128, EMB / 64), 256, 0, stream>>>(
        ctxb, Wot, NTOK, EMB, EMB, x1, nullptr, bo, x);

    // LN2
    ln_kernel<<<NTOK, 256, 0, stream>>>(x1, g2, s2, hbuf);

    // FFN1 + gelu -> bf16 mid  (8-phase 256^2)
    gemm8p<2><<<dim3(NTOK / 256, FFN / 256), 512, 131072, stream>>>(
        hbuf, W1t, EMB, FFN, midb, nullptr, b1);

    // FFN2 split-K=3 (8-phase 256^2, bf16 partials) + reduce
    gemm8p<3><<<dim3(NTOK / 256, EMB / 256, 3), 512, 131072, stream>>>(
        midb, W2t, FFN, EMB, p01, p2, nullptr);
    ffn2_reduce<<<dim3(2048), 256, 0, stream>>>(x1, p01, p2, b2, (float*)d_out);
}

// Round 22
// 226.815 us; speedup vs baseline: 1.0153x; 1.0053x over previous
//
#include <hip/hip_runtime.h>
#include <hip/hip_bf16.h>
#include <math.h>
#include <stdint.h>

typedef __bf16 bf16;
typedef __bf16 bf16x2 __attribute__((ext_vector_type(2)));
typedef __bf16 bf16x4 __attribute__((ext_vector_type(4)));
typedef __bf16 bf16x8 __attribute__((ext_vector_type(8)));
typedef float f32x4 __attribute__((ext_vector_type(4)));
typedef float f32x16 __attribute__((ext_vector_type(16)));
typedef unsigned uint2v __attribute__((ext_vector_type(2)));
typedef unsigned uint4v __attribute__((ext_vector_type(4)));

#define MFMA16(a, b, c) __builtin_amdgcn_mfma_f32_16x16x32_bf16((a), (b), (c), 0, 0, 0)
#define MFMA32(a, b, c) __builtin_amdgcn_mfma_f32_32x32x16_bf16((a), (b), (c), 0, 0, 0)

constexpr int EMB = 1024;
constexpr int SEQ = 2048;
constexpr int BATCH = 2;
constexpr int NTOK = BATCH * SEQ;   // 4096
constexpr int FFN = 4 * EMB;        // 4096
constexpr int HEADS = 16;
constexpr int HDIM = 64;

// q pre-scale: 1/sqrt(64) * log2(e)  (softmax runs in exp2 domain)
#define QSCALE 0.18033688011112042f

// async 16B global -> LDS (wave-uniform base + lane*16 destination)
__device__ __forceinline__ void gload16(const void* g, void* l) {
    __builtin_amdgcn_global_load_lds(
        (const __attribute__((address_space(1))) void*)g,
        (__attribute__((address_space(3))) void*)l,
        16, 0, 0);
}

// cross-half (lane i <-> lane i+32) max/sum via v_permlane32_swap (VALU pipe)
__device__ __forceinline__ float xhalf_max(float x) {
    unsigned u = __float_as_uint(x);
    uint2v r = __builtin_amdgcn_permlane32_swap(u, u, false, false);
    return fmaxf(__uint_as_float(r[0]), __uint_as_float(r[1]));
}
__device__ __forceinline__ float xhalf_sum(float x) {
    unsigned u = __float_as_uint(x);
    uint2v r = __builtin_amdgcn_permlane32_swap(u, u, false, false);
    return __uint_as_float(r[0]) + __uint_as_float(r[1]);
}

__device__ __forceinline__ unsigned pkbf(float a, float b) {
    bf16x2 v;
    v[0] = (bf16)a;
    v[1] = (bf16)b;
    return __builtin_bit_cast(unsigned, v);
}

// gelu_tanh(u) = u * sigmoid(2w), w = c*(u + 0.044715 u^3); exp2 domain
__device__ __forceinline__ float gelu_f(float u) {
    float w_ = 0.7978845608028654f * (u + 0.044715f * u * u * u);
    float z = __builtin_amdgcn_exp2f(-2.8853900817779268f * w_);
    return u / (1.f + z);
}

// ---------------- LayerNorm: fp32 in -> bf16 out --------------------------
__global__ __launch_bounds__(256) void ln_kernel(const float* __restrict__ x,
                                                 const float* __restrict__ g,
                                                 const float* __restrict__ b,
                                                 bf16* __restrict__ out) {
    int row = blockIdx.x;
    int t = threadIdx.x;
    float4 v = reinterpret_cast<const float4*>(x + (size_t)row * EMB)[t];
    float s = v.x + v.y + v.z + v.w;
    float s2 = v.x * v.x + v.y * v.y + v.z * v.z + v.w * v.w;
#pragma unroll
    for (int o = 1; o < 64; o <<= 1) {
        s += __shfl_xor(s, o);
        s2 += __shfl_xor(s2, o);
    }
    __shared__ float ps[4], ps2[4];
    int w = t >> 6;
    if ((t & 63) == 0) { ps[w] = s; ps2[w] = s2; }
    __syncthreads();
    s = ps[0] + ps[1] + ps[2] + ps[3];
    s2 = ps2[0] + ps2[1] + ps2[2] + ps2[3];
    float mean = s * (1.f / EMB);
    float var = s2 * (1.f / EMB) - mean * mean;
    float rstd = rsqrtf(var + 1e-5f);
    float4 gv = reinterpret_cast<const float4*>(g)[t];
    float4 bv = reinterpret_cast<const float4*>(b)[t];
    bf16* op = out + (size_t)row * EMB + t * 4;
    op[0] = (bf16)(gv.x * (v.x - mean) * rstd + bv.x);
    op[1] = (bf16)(gv.y * (v.y - mean) * rstd + bv.y);
    op[2] = (bf16)(gv.z * (v.z - mean) * rstd + bv.z);
    op[3] = (bf16)(gv.w * (v.w - mean) * rstd + bv.w);
}

// ---- fused transpose + cast: all 6 weights, W[K][N] f32 -> Wt[N][K] bf16 --
__global__ __launch_bounds__(256) void transpose_all(
    const float* __restrict__ Wq, const float* __restrict__ Wk,
    const float* __restrict__ Wv, const float* __restrict__ Wo,
    const float* __restrict__ W1, const float* __restrict__ W2,
    bf16* __restrict__ Wqkvt, bf16* __restrict__ Wot,
    bf16* __restrict__ W1t, bf16* __restrict__ W2t) {
    int b = blockIdx.x;
    const float* W;
    bf16* Wt;
    int K, N, tile;
    if (b < 4096) {
        int w = b >> 10;
        tile = b & 1023;
        W = (w == 0) ? Wq : (w == 1) ? Wk : (w == 2) ? Wv : Wo;
        Wt = (w == 3) ? Wot : Wqkvt + (size_t)w * EMB * EMB;
        K = EMB; N = EMB;
    } else if (b < 8192) {
        tile = b - 4096; W = W1; Wt = W1t; K = EMB; N = FFN;
    } else {
        tile = b - 8192; W = W2; Wt = W2t; K = FFN; N = EMB;
    }
    int ntx = N / 32;
    int n0 = (tile % ntx) * 32, k0 = (tile / ntx) * 32;
    __shared__ float tl[32][33];
    int tx = threadIdx.x & 31, ty = threadIdx.x >> 5;  // 32 x 8
#pragma unroll
    for (int i = 0; i < 4; i++)
        tl[ty + 8 * i][tx] = W[(size_t)(k0 + ty + 8 * i) * N + n0 + tx];
    __syncthreads();
#pragma unroll
    for (int i = 0; i < 4; i++)
        Wt[(size_t)(n0 + ty + 8 * i) * K + k0 + tx] = (bf16)tl[tx][ty + 8 * i];
}

// ---------------- V transpose: [B,H,S,64] -> [B,H,64,S] bf16 --------------
__global__ __launch_bounds__(256) void vtrans(const bf16* __restrict__ v,
                                              bf16* __restrict__ vt) {
    int bh = blockIdx.y;
    int s0 = blockIdx.x * 64;
    const bf16* src = v + (size_t)bh * SEQ * HDIM + (size_t)s0 * HDIM;
    bf16* dst = vt + (size_t)bh * HDIM * SEQ + s0;
    __shared__ bf16 tile[64][72];
    int t = threadIdx.x;
    int s = t >> 2, d0 = (t & 3) * 16;
    bf16x8 a = *reinterpret_cast<const bf16x8*>(src + s * HDIM + d0);
    bf16x8 b = *reinterpret_cast<const bf16x8*>(src + s * HDIM + d0 + 8);
#pragma unroll
    for (int e = 0; e < 8; e++) {
        tile[d0 + e][s] = a[e];
        tile[d0 + 8 + e][s] = b[e];
    }
    __syncthreads();
    int d = t >> 2, c0 = (t & 3) * 16;
    bf16x8 o0 = *reinterpret_cast<const bf16x8*>(&tile[d][c0]);
    bf16x8 o1 = *reinterpret_cast<const bf16x8*>(&tile[d][c0 + 8]);
    *reinterpret_cast<bf16x8*>(dst + (size_t)d * SEQ + c0) = o0;
    *reinterpret_cast<bf16x8*>(dst + (size_t)d * SEQ + c0 + 8) = o1;
}

// ---------------- 8-phase 256x256 GEMM, counted-vmcnt (T2+T3+T4+T5) -------
// MODE 0: fused QKV scatter -> bf16 q/k/v [B,H,S,64] (q scaled QSCALE)
// MODE 2: out bf16 = gelu(acc + bias)
// MODE 3: bf16 partial tile -> z<2: outB + z*NTOK*EMB ; z==2: outB2
template <int MODE>
__global__ __launch_bounds__(512, 1) void gemm8p(const bf16* __restrict__ A,
                                                 const bf16* __restrict__ Bt,
                                                 int K, int N,
                                                 bf16* __restrict__ outB,
                                                 bf16* __restrict__ outB2,
                                                 const float* __restrict__ bias) {
    extern __shared__ char smem[];  // [buf][A 32K | B 32K] x2 = 128 KiB
    int t = threadIdx.x;
    int wave = t >> 6, lane = t & 63;
    int wr = wave >> 2, wc = wave & 3;      // 2 x 4 wave grid
    int lr = lane & 15, lg = lane >> 4;
    int row0 = blockIdx.x * 256;
    int col0 = blockIdx.y * 256;

    int tilesAll = K / 64;
    int nz = gridDim.z, z = blockIdx.z;
    int base = tilesAll / nz, rem = tilesAll - base * nz;
    int myT = base + (z < rem ? 1 : 0);
    int tBeg = z * base + (z < rem ? z : rem);

    const char* aSrc[4];
    const char* bSrc[4];
#pragma unroll
    for (int i = 0; i < 4; i++) {
        int f = t + i * 512;
        int gr = f >> 3, gk = f & 7;
        aSrc[i] = (const char*)A + ((size_t)(row0 + gr) * K + ((gk ^ (gr & 7)) << 3)) * 2
                  + (size_t)tBeg * 128;
        bSrc[i] = (const char*)Bt + ((size_t)(col0 + gr) * K + ((gk ^ (gr & 7)) << 3)) * 2
                  + (size_t)tBeg * 128;
    }

    f32x4 acc[8][4];
#pragma unroll
    for (int m = 0; m < 8; m++)
#pragma unroll
        for (int n = 0; n < 4; n++) acc[m][n] = f32x4{0.f, 0.f, 0.f, 0.f};

    // prologue: stage tile 0 into buf 0; issue order B0,B1,B2,B3,A0,A2,A1,A3
    gload16(bSrc[0], smem + 32768 + (t + 0 * 512) * 16);
    gload16(bSrc[1], smem + 32768 + (t + 1 * 512) * 16);
    gload16(bSrc[2], smem + 32768 + (t + 2 * 512) * 16);
    gload16(bSrc[3], smem + 32768 + (t + 3 * 512) * 16);
    gload16(aSrc[0], smem + (t + 0 * 512) * 16);
    gload16(aSrc[2], smem + (t + 2 * 512) * 16);
    gload16(aSrc[1], smem + (t + 1 * 512) * 16);
    gload16(aSrc[3], smem + (t + 3 * 512) * 16);
    asm volatile("s_waitcnt vmcnt(2)" ::: "memory");
    __builtin_amdgcn_s_barrier();

    for (int tk = 0; tk < myT; tk++) {
        int cur = tk & 1;
        const char* la = smem + cur * 65536;
        const char* lb = la + 32768;
        char* na = smem + (cur ^ 1) * 65536;
        bool stage = (tk + 1 < myT);

        bf16x8 bfr[2][4];
#pragma unroll
        for (int ph = 0; ph < 4; ph++) {
            constexpr int PH_KH[4] = {0, 0, 1, 1};
            constexpr int PH_MH[4] = {0, 1, 0, 1};
            const int kh = PH_KH[ph], mh = PH_MH[ph];
            bf16x8 afr[4];
#pragma unroll
            for (int m = 0; m < 4; m++) {
                int row = wr * 128 + (mh * 4 + m) * 16 + lr;
                int gk = kh * 4 + lg;
                afr[m] = *reinterpret_cast<const bf16x8*>(
                    la + row * 128 + ((gk ^ (row & 7)) << 4));
            }
            if (mh == 0) {
#pragma unroll
                for (int n = 0; n < 4; n++) {
                    int row = wc * 64 + n * 16 + lr;
                    int gk = kh * 4 + lg;
                    bfr[kh][n] = *reinterpret_cast<const bf16x8*>(
                        lb + row * 128 + ((gk ^ (row & 7)) << 4));
                }
            }
            if (stage) {
                if (ph == 0) {
                    gload16(bSrc[0] + 128, na + 32768 + (t + 0 * 512) * 16);
                    gload16(bSrc[1] + 128, na + 32768 + (t + 1 * 512) * 16);
                } else if (ph == 1) {
                    gload16(bSrc[2] + 128, na + 32768 + (t + 2 * 512) * 16);
                    gload16(bSrc[3] + 128, na + 32768 + (t + 3 * 512) * 16);
                } else if (ph == 2) {
                    gload16(aSrc[0] + 128, na + (t + 0 * 512) * 16);
                    gload16(aSrc[2] + 128, na + (t + 2 * 512) * 16);
                } else {
                    gload16(aSrc[1] + 128, na + (t + 1 * 512) * 16);
                    gload16(aSrc[3] + 128, na + (t + 3 * 512) * 16);
                }
            }
            __builtin_amdgcn_s_barrier();
            __builtin_amdgcn_s_setprio(1);
#pragma unroll
            for (int m = 0; m < 4; m++)
#pragma unroll
                for (int n = 0; n < 4; n++)
                    acc[mh * 4 + m][n] = MFMA16(afr[m], bfr[kh][n], acc[mh * 4 + m][n]);
            __builtin_amdgcn_s_setprio(0);
            if (ph == 0 || ph == 3)
                asm volatile("s_waitcnt vmcnt(2)" ::: "memory");
            __builtin_amdgcn_s_barrier();
        }
#pragma unroll
        for (int i = 0; i < 4; i++) { aSrc[i] += 128; bSrc[i] += 128; }
    }

    float bi[4];
    if (MODE == 2) {
#pragma unroll
        for (int n = 0; n < 4; n++) bi[n] = bias[col0 + wc * 64 + n * 16 + lr];
    }
    bf16* pd = outB;
    if (MODE == 3) pd = (z < 2) ? outB + (size_t)z * ((size_t)NTOK * EMB) : outB2;
#pragma unroll
    for (int mf = 0; mf < 8; mf++) {
#pragma unroll
        for (int r = 0; r < 4; r++) {
            int row = row0 + wr * 128 + mf * 16 + 4 * lg + r;
#pragma unroll
            for (int n = 0; n < 4; n++) {
                int col = col0 + wc * 64 + n * 16 + lr;
                float v = acc[mf][n][r];
                if (MODE == 0) {
                    int b_ = row >> 11, s_ = row & 2047;
                    int which = col >> 10, rem_ = col & 1023;
                    int h_ = rem_ >> 6, d_ = rem_ & 63;
                    float sc = (which == 0) ? QSCALE : 1.0f;
                    outB[(size_t)which * (NTOK * EMB) +
                         (((size_t)(b_ * HEADS + h_) * SEQ + s_) << 6) + d_] =
                        (bf16)(v * sc);
                } else if (MODE == 2) {
                    outB[(size_t)row * N + col] = (bf16)gelu_f(v + bi[n]);
                } else {
                    pd[(size_t)row * N + col] = (bf16)v;
                }
            }
        }
    }
}

// ------- FFN2 reduce: out = x1 + p0 + p1 + p2 + bias (all fp32 out) -------
__global__ __launch_bounds__(256) void ffn2_reduce(const float* __restrict__ x1,
                                                   const bf16* __restrict__ p01,
                                                   const bf16* __restrict__ p2,
                                                   const float* __restrict__ bias,
                                                   float* __restrict__ out) {
    constexpr int UNITS = NTOK * EMB / 4;
    const bf16* p1 = p01 + (size_t)NTOK * EMB;
    for (int i = blockIdx.x * 256 + threadIdx.x; i < UNITS; i += gridDim.x * 256) {
        float4 r = reinterpret_cast<const float4*>(x1)[i];
        float4 bv = reinterpret_cast<const float4*>(bias)[i & (EMB / 4 - 1)];
        bf16x4 a0 = reinterpret_cast<const bf16x4*>(p01)[i];
        bf16x4 a1 = reinterpret_cast<const bf16x4*>(p1)[i];
        bf16x4 a2 = reinterpret_cast<const bf16x4*>(p2)[i];
        r.x += (float)a0[0] + (float)a1[0] + (float)a2[0] + bv.x;
        r.y += (float)a0[1] + (float)a1[1] + (float)a2[1] + bv.y;
        r.z += (float)a0[2] + (float)a1[2] + (float)a2[2] + bv.z;
        r.w += (float)a0[3] + (float)a1[3] + (float)a2[3] + bv.w;
        reinterpret_cast<float4*>(out)[i] = r;
    }
}

// ---------------- LDS-staged GEMM (m97 structure) -------------------------
// MODE 1: out f32 = resid + acc + bias
template <int BM, int BN, int BK, int MODE>
__global__ __launch_bounds__(256) void gemm_lds(const bf16* __restrict__ A,
                                                const bf16* __restrict__ Bt,
                                                int M, int N, int K,
                                                float* __restrict__ outF,
                                                bf16* __restrict__ outB,
                                                const float* __restrict__ bias,
                                                const float* __restrict__ resid) {
    constexpr int MR = BM / 32;
    constexpr int NR = BN / 32;
    constexpr int ACH = (BM * BK * 2) / 4096;
    constexpr int BCH = (BN * BK * 2) / 4096;
    __shared__ bf16 sA[BM * BK];
    __shared__ bf16 sB[BN * BK];
    int t = threadIdx.x;
    int wave = t >> 6, lane = t & 63;
    int wr = wave >> 1, wc = wave & 1;
    int lr = lane & 15, lg = lane >> 4;
    int row0 = blockIdx.x * BM;
    int col0 = blockIdx.y * BN;

    const char* aS[ACH];
    const char* bS[BCH];
#pragma unroll
    for (int c = 0; c < ACH; c++) {
        int o = (t + c * 256) * 16;
        aS[c] = (const char*)A + (size_t)(row0 + o / (2 * BK)) * K * 2 + (o & (2 * BK - 1));
    }
#pragma unroll
    for (int c = 0; c < BCH; c++) {
        int o = (t + c * 256) * 16;
        bS[c] = (const char*)Bt + (size_t)(col0 + o / (2 * BK)) * K * 2 + (o & (2 * BK - 1));
    }

    f32x4 acc[MR][NR];
#pragma unroll
    for (int m = 0; m < MR; m++)
#pragma unroll
        for (int n = 0; n < NR; n++) acc[m][n] = f32x4{0.f, 0.f, 0.f, 0.f};

    for (int k0 = 0; k0 < K; k0 += BK) {
        __syncthreads();
#pragma unroll
        for (int c = 0; c < ACH; c++)
            gload16(aS[c], (char*)sA + (t + c * 256) * 16);
#pragma unroll
        for (int c = 0; c < BCH; c++)
            gload16(bS[c], (char*)sB + (t + c * 256) * 16);
#pragma unroll
        for (int c = 0; c < ACH; c++) aS[c] += 2 * BK;
#pragma unroll
        for (int c = 0; c < BCH; c++) bS[c] += 2 * BK;
        __syncthreads();

#pragma unroll
        for (int ks = 0; ks < BK / 32; ks++) {
            bf16x8 a[MR], b[NR];
#pragma unroll
            for (int m = 0; m < MR; m++)
                a[m] = *reinterpret_cast<const bf16x8*>(
                    sA + (wr * (BM / 2) + m * 16 + lr) * BK + ks * 32 + 8 * lg);
#pragma unroll
            for (int n = 0; n < NR; n++)
                b[n] = *reinterpret_cast<const bf16x8*>(
                    sB + (wc * (BN / 2) + n * 16 + lr) * BK + ks * 32 + 8 * lg);
#pragma unroll
            for (int m = 0; m < MR; m++)
#pragma unroll
                for (int n = 0; n < NR; n++)
                    acc[m][n] = MFMA16(a[m], b[n], acc[m][n]);
        }
    }

#pragma unroll
    for (int m = 0; m < MR; m++) {
#pragma unroll
        for (int r = 0; r < 4; r++) {
            int row = row0 + wr * (BM / 2) + m * 16 + 4 * lg + r;
#pragma unroll
            for (int n = 0; n < NR; n++) {
                int col = col0 + wc * (BN / 2) + n * 16 + lr;
                float v = acc[m][n][r];
                size_t idx = (size_t)row * N + col;
                outF[idx] = resid[idx] + v + bias[col];
            }
        }
    }
}

// ---------------- causal flash attention (v13: single-V-buffer) ------------
// v12b with sV reduced to a SINGLE buffer (V(c+1) staged after a post-PV
// barrier): LDS 64 -> 48 KB -> 3 blocks/CU (12 waves/CU, +50% TLP).
// Per chunk: {issue K(c+1) -> kbuf dbuf | QK(c)+softmax | __syncthreads
// (publishes V(c)+K(c+1)) | PV(c) from sV | s_barrier | issue V(c+1) -> sV}.
// Hazards audited: kbuf WAR (K(c+1) issue after barrier covering QK(c-1)
// reads), sV WAR (V(c+1) issue after post-PV barrier), RAW via the full
// drain in __syncthreads.
__global__ __launch_bounds__(256, 3) void attn_kernel(const bf16* __restrict__ q,
                                                      const bf16* __restrict__ k,
                                                      const bf16* __restrict__ vt,
                                                      bf16* __restrict__ ctx) {
    int wg = blockIdx.x;
    int wgid = (wg & 7) * 64 + (wg >> 3);   // bijective: 512 = 8 XCD * 64
    int bh = wgid >> 4;                     // 16 blocks/head, 4 heads/XCD
    int pair = wgid & 15;
    const bf16* qh = q + (size_t)bh * SEQ * HDIM;
    const bf16* kh = k + (size_t)bh * SEQ * HDIM;
    const bf16* vh = vt + (size_t)bh * HDIM * SEQ;  // [64][2048]
    int t = threadIdx.x;
    int wave = t >> 6, lane = t & 63;
    int ql = lane & 31, hi = lane >> 5;

    int s64 = (wave < 2) ? (31 - pair) : pair;   // q-span in 64-row units
    int qrow = s64 * 64 + (wave & 1) * 32;
    int myNc = (s64 >> 1) + 1;                   // 128-key chunks this wave needs
    int ncAll = ((31 - pair) >> 1) + 1;          // chunks staged (heavy range)

    __shared__ bf16 sK[2][128 * 64];   // [key][d], granule-swizzled (16 KB/buf)
    __shared__ bf16 sV[2][64 * 64];    // single buf: [half][d][key] (16 KB)

    int grow = t >> 3, gg = t & 7;
    const bf16* kS[4];
#pragma unroll
    for (int i = 0; i < 4; i++)
        kS[i] = kh + (size_t)(grow + 32 * i) * HDIM + ((gg ^ ((grow + 32 * i) & 7)) << 3);
    const bf16* vS[2];
#pragma unroll
    for (int i = 0; i < 2; i++)
        vS[i] = vh + (size_t)(grow + 32 * i) * SEQ + ((gg ^ ((grow + 32 * i) & 7)) << 3);
    char* kD = (char*)&sK[0][0] + wave * 1024;
    char* vD = (char*)&sV[0][0] + wave * 1024;

    int b_ = bh >> 4, h_ = bh & 15;

    // Q fragments (B-operand): col=q=ql, k = 8*hi+e over d-slices ks*16
    bf16x8 qf[4];
#pragma unroll
    for (int ks = 0; ks < 4; ks++)
        qf[ks] = *reinterpret_cast<const bf16x8*>(
            qh + (size_t)(qrow + ql) * HDIM + ks * 16 + 8 * hi);

    f32x16 o0, o1;
#pragma unroll
    for (int r = 0; r < 16; r++) { o0[r] = 0.f; o1[r] = 0.f; }
    float mx = -1e30f, lsum = 0.f;  // per-lane state for q = qrow + ql

    // prologue: stage chunk 0 (K -> kbuf0, V -> sV)
#pragma unroll
    for (int i = 0; i < 4; i++) gload16(kS[i], kD + i * 4096);
#pragma unroll
    for (int hh = 0; hh < 2; hh++)
#pragma unroll
        for (int i = 0; i < 2; i++)
            gload16(vS[i] + 64 * hh, vD + hh * 8192 + i * 4096);
    __syncthreads();

    for (int c = 0; c < ncAll; c++) {
        int c0 = c * 128;
        bool haveNext = (c + 1 < ncAll);
        if (haveNext) {
            int nb = (c + 1) & 1;
            int cn = c0 + 128;
#pragma unroll
            for (int i = 0; i < 4; i++)
                gload16(kS[i] + (size_t)cn * HDIM, kD + nb * 16384 + i * 4096);
        }

        f32x16 st[4];
        if (c < myNc) {
            const char* kb_ = (const char*)&sK[c & 1][0];

            // ---- QK^T swapped: st[kg] keys kg*32.., cols = q (per-lane) ----
#pragma unroll
            for (int kg = 0; kg < 4; kg++)
#pragma unroll
                for (int r = 0; r < 16; r++) st[kg][r] = 0.f;
#pragma unroll
            for (int ks = 0; ks < 4; ks++) {
                int so = ((2 * ks + hi) ^ (ql & 7)) << 4;
#pragma unroll
                for (int kg = 0; kg < 4; kg++) {
                    bf16x8 kA = *reinterpret_cast<const bf16x8*>(
                        kb_ + (kg * 32 + ql) * 128 + so);
                    st[kg] = MFMA32(kA, qf[ks], st[kg]);
                }
            }

            if (c == myNc - 1) {  // diagonal chunk: causal mask (key > q)
#pragma unroll
                for (int kg = 0; kg < 4; kg++)
#pragma unroll
                    for (int r = 0; r < 16; r++) {
                        int kl = c0 + kg * 32 + (r & 3) + 8 * (r >> 2) + 4 * hi;
                        if (kl > qrow + ql) st[kg][r] = -1e30f;
                    }
            }

            // ---- softmax: per-lane row (q = ql), exp2 domain, defer-max ----
            float pmax = -1e30f;
#pragma unroll
            for (int kg = 0; kg < 4; kg++)
#pragma unroll
                for (int r = 0; r < 16; r++) pmax = fmaxf(pmax, st[kg][r]);
            pmax = xhalf_max(pmax);
            float mxold = mx;
            bool defer = (pmax <= mxold + 8.0f);
            float mn = defer ? mxold : fmaxf(mxold, pmax);
            mx = mn;
            float ps = 0.f;
#pragma unroll
            for (int kg = 0; kg < 4; kg++)
#pragma unroll
                for (int r = 0; r < 16; r++) {
                    st[kg][r] = __builtin_amdgcn_exp2f(st[kg][r] - mn);
                    ps += st[kg][r];
                }
            ps = xhalf_sum(ps);
            if (!__all(defer)) {
                float scl = __builtin_amdgcn_exp2f(mxold - mn);  // 1 on defer lanes
                lsum = lsum * scl + ps;
#pragma unroll
                for (int r = 0; r < 16; r++) { o0[r] *= scl; o1[r] *= scl; }
            } else {
                lsum += ps;
            }
        }

        // publishes V(c) (staged end of c-1 / prologue) and K(c+1) to all waves
        __syncthreads();

        if (c < myNc) {
            // ---- PV swapped, P B-frags built in-register ----
#pragma unroll
            for (int kg = 0; kg < 4; kg++) {
                f32x16 P = st[kg];
#pragma unroll
                for (int sub = 0; sub < 2; sub++) {
                    int ks8 = 2 * kg + sub;
                    int bs = 8 * sub;
                    unsigned X0 = pkbf(P[bs + 0], P[bs + 1]);
                    unsigned X1 = pkbf(P[bs + 2], P[bs + 3]);
                    unsigned Y0 = pkbf(P[bs + 4], P[bs + 5]);
                    unsigned Y1 = pkbf(P[bs + 6], P[bs + 7]);
                    uint2v s0 = __builtin_amdgcn_permlane32_swap(X0, Y0, false, false);
                    uint2v s1 = __builtin_amdgcn_permlane32_swap(X1, Y1, false, false);
                    uint4v uw;
                    uw[0] = s0[0];
                    uw[1] = s1[0];
                    uw[2] = s0[1];
                    uw[3] = s1[1];
                    bf16x8 pb = __builtin_bit_cast(bf16x8, uw);
                    const char* vb_ = (const char*)&sV[ks8 >> 2][0];
                    int kss = ks8 & 3;
                    int so = ((2 * kss + hi) ^ (ql & 7)) << 4;
                    bf16x8 vA0 = *reinterpret_cast<const bf16x8*>(vb_ + ql * 128 + so);
                    bf16x8 vA1 = *reinterpret_cast<const bf16x8*>(vb_ + (32 + ql) * 128 + so);
                    o0 = MFMA32(vA0, pb, o0);
                    o1 = MFMA32(vA1, pb, o1);
                }
            }
        }

        __builtin_amdgcn_s_barrier();   // all sV reads done

        if (haveNext) {
            int cn = c0 + 128;
#pragma unroll
            for (int hh = 0; hh < 2; hh++)
#pragma unroll
                for (int i = 0; i < 2; i++)
                    gload16(vS[i] + cn + 64 * hh, vD + hh * 8192 + i * 4096);
        }
    }

    // ---- epilogue: per-lane normalize; q = qrow+ql, d = 8j+4hi+e (+32) ----
    float inv = 1.f / lsum;
    size_t base = ((size_t)b_ * SEQ + qrow + ql) * EMB + h_ * HDIM;
#pragma unroll
    for (int j = 0; j < 4; j++) {
        bf16x4 w0, w1;
#pragma unroll
        for (int e = 0; e < 4; e++) {
            w0[e] = (bf16)(o0[4 * j + e] * inv);
            w1[e] = (bf16)(o1[4 * j + e] * inv);
        }
        *reinterpret_cast<bf16x4*>(ctx + base + 8 * j + 4 * hi) = w0;
        *reinterpret_cast<bf16x4*>(ctx + base + 32 + 8 * j + 4 * hi) = w1;
    }
}

// ---------------- launch ---------------------------------------------------
extern "C" void kernel_launch(void* const* d_in, const int* in_sizes, int n_in,
                              void* d_out, int out_size, void* d_ws, size_t ws_size,
                              hipStream_t stream) {
    const float* x  = (const float*)d_in[0];
    const float* Wq = (const float*)d_in[1];
    const float* Wk = (const float*)d_in[2];
    const float* Wv = (const float*)d_in[3];
    const float* Wo = (const float*)d_in[4];
    const float* bo = (const float*)d_in[5];
    const float* W1 = (const float*)d_in[6];
    const float* b1 = (const float*)d_in[7];
    const float* W2 = (const float*)d_in[8];
    const float* b2 = (const float*)d_in[9];
    const float* g1 = (const float*)d_in[10];
    const float* s1 = (const float*)d_in[11];
    const float* g2 = (const float*)d_in[12];
    const float* s2 = (const float*)d_in[13];

    const size_t MB = 1ull << 20;
    char* w = (char*)d_ws;
    bf16* Wqkvt = (bf16*)(w + 0 * MB);            // [3072][1024], dead after QKV
    bf16* Wot = (bf16*)(w + 6 * MB);              // dead after Wo
    bf16* W1t = (bf16*)(w + 8 * MB);              // dead after FFN1
    bf16* W2t = (bf16*)(w + 16 * MB);             // live till FFN2
    bf16* hbuf = (bf16*)(w + 24 * MB);            // h1 / h2, dead after FFN1
    bf16* vtb  = (bf16*)(w + 24 * MB);            // aliases hbuf (QKV..attn window)
    bf16* qkvb = (bf16*)(w + 32 * MB);            // q/k/v, dead after attn
    bf16* qb   = (bf16*)(w + 32 * MB);
    bf16* kb   = (bf16*)(w + 40 * MB);
    bf16* vb   = (bf16*)(w + 48 * MB);
    bf16* ctxb = (bf16*)(w + 56 * MB);            // dead after Wo
    bf16* midb = (bf16*)(w + 32 * MB);            // 32-64, over dead qkv/ctx
    float* x1  = (float*)(w + 64 * MB);           // live till ffn2_reduce
    bf16* p01  = (bf16*)(w + 0 * MB);             // FFN2 partials z0,z1 (16 MB)
    bf16* p2   = (bf16*)(w + 24 * MB);            // partial z2 (8 MB, dead hbuf)

    // allow 128 KiB dynamic LDS for the 8-phase GEMMs
    hipFuncSetAttribute(reinterpret_cast<const void*>(gemm8p<0>),
                        hipFuncAttributeMaxDynamicSharedMemorySize, 131072);
    hipFuncSetAttribute(reinterpret_cast<const void*>(gemm8p<2>),
                        hipFuncAttributeMaxDynamicSharedMemorySize, 131072);
    hipFuncSetAttribute(reinterpret_cast<const void*>(gemm8p<3>),
                        hipFuncAttributeMaxDynamicSharedMemorySize, 131072);

    // all 6 weight transposes in one dispatch (fp32 -> bf16 [N][K])
    transpose_all<<<dim3(12288), 256, 0, stream>>>(Wq, Wk, Wv, Wo, W1, W2,
                                                   Wqkvt, Wot, W1t, W2t);

    // LN1
    ln_kernel<<<NTOK, 256, 0, stream>>>(x, g1, s1, hbuf);

    // fused QKV projection: [4096,1024] @ [3072,1024]^T  (8-phase 256^2)
    gemm8p<0><<<dim3(NTOK / 256, 3072 / 256), 512, 131072, stream>>>(
        hbuf, Wqkvt, EMB, 3072, qkvb, nullptr, nullptr);

    // V -> V^T  [B,H,64,S]
    vtrans<<<dim3(SEQ / 64, BATCH * HEADS), 256, 0, stream>>>(vb, vtb);

    // attention (v13: single-V-buffer, 3 blocks/CU)
    attn_kernel<<<dim3(512), 256, 0, stream>>>(qb, kb, vtb, ctxb);

    // output projection + residual -> x1 (f32)  (m97 128x64, BK=32)
    gemm_lds<128, 64, 32, 1><<<dim3(NTOK / 128, EMB / 64), 256, 0, stream>>>(
        ctxb, Wot, NTOK, EMB, EMB, x1, nullptr, bo, x);

    // LN2
    ln_kernel<<<NTOK, 256, 0, stream>>>(x1, g2, s2, hbuf);

    // FFN1 + gelu -> bf16 mid  (8-phase 256^2)
    gemm8p<2><<<dim3(NTOK / 256, FFN / 256), 512, 131072, stream>>>(
        hbuf, W1t, EMB, FFN, midb, nullptr, b1);

    // FFN2 split-K=3 (8-phase 256^2, bf16 partials) + reduce
    gemm8p<3><<<dim3(NTOK / 256, EMB / 256, 3), 512, 131072, stream>>>(
        midb, W2t, FFN, EMB, p01, p2, nullptr);
    ffn2_reduce<<<dim3(2048), 256, 0, stream>>>(x1, p01, p2, b2, (float*)d_out);
}